// Round 6
// baseline (394.742 us; speedup 1.0000x reference)
//
#include <hip/hip_runtime.h>

#define NPIX 1024
#define CIN  256
#define EPSV 1e-5f
#define SP 264
#define AP 72
#define BKA 264

typedef __attribute__((ext_vector_type(8))) short bf16x8;
typedef __attribute__((ext_vector_type(4))) float f32x4;

__device__ __forceinline__ short f2bf(float f) {
  unsigned u = __float_as_uint(f);
  unsigned r = (u + 0x7FFFu + ((u >> 16) & 1u)) >> 16;
  return (short)r;
}
__device__ __forceinline__ float b2f(short s) {
  return __uint_as_float(((unsigned)(unsigned short)s) << 16);
}

// ---------------- K0a: non-kv weights fp32 -> bf16 --------------------------
__global__ __launch_bounds__(256) void wcvt(
    const float* __restrict__ wq, const float* __restrict__ wih,
    const float* __restrict__ whh, const float* __restrict__ w1,
    const float* __restrict__ w2,
    short* __restrict__ wq_b, short* __restrict__ wih_b, short* __restrict__ whh_b,
    short* __restrict__ w1_b, short* __restrict__ w2_b) {
  int id = blockIdx.x * 256 + threadIdx.x;
  if      (id <  65536) wq_b [id         ] = f2bf(wq [id         ]);
  else if (id < 262144) wih_b[id -  65536] = f2bf(wih[id -  65536]);
  else if (id < 458752) whh_b[id - 262144] = f2bf(whh[id - 262144]);
  else if (id < 524288) w1_b [id - 458752] = f2bf(w1 [id - 458752]);
  else if (id < 589824) w2_b [id - 524288] = f2bf(w2 [id - 524288]);
}

// ---------------- K0b: wkv' = g*w (bf16) + A=sum(g*w), B=sum(b*w) -----------
__global__ __launch_bounds__(256) void wfold(
    const float* __restrict__ wk, const float* __restrict__ wv,
    const float* __restrict__ g, const float* __restrict__ bet,
    short* __restrict__ wkv_b, float* __restrict__ kvA, float* __restrict__ kvB) {
  __shared__ float ra[4], rb[4];
  int d = blockIdx.x;                 // 0..511
  int t = threadIdx.x;
  const float* wrow = (d < 256) ? (wk + (size_t)d * 256) : (wv + (size_t)(d - 256) * 256);
  float w = wrow[t], gg = g[t], bb = bet[t];
  float pa = gg * w, pb = bb * w;
  wkv_b[(size_t)d * 256 + t] = f2bf(pa);
  #pragma unroll
  for (int m = 1; m < 64; m <<= 1) { pa += __shfl_xor(pa, m); pb += __shfl_xor(pb, m); }
  int wave = t >> 6, lane = t & 63;
  if (lane == 0) { ra[wave] = pa; rb[wave] = pb; }
  __syncthreads();
  if (t == 0) {
    kvA[d] = ra[0] + ra[1] + ra[2] + ra[3];
    kvB[d] = rb[0] + rb[1] + rb[2] + rb[3];
  }
}

// ---------------- K1a: transpose x -> xT bf16 + LN stats (no LDS tile) ------
// grid 512 = (8 pt, 64 b). Block: 128 pixels x 256 c.
// Quad shfl 4x4 transpose; writes 16B/lane (64B/quad) coalesced.
__global__ __launch_bounds__(256) void xt_stats(
    const float* __restrict__ x, short* __restrict__ xT,
    float* __restrict__ mu, float* __restrict__ rstd) {
  __shared__ float ps[2][128], pq[2][128];
  int t = threadIdx.x;
  int pt = blockIdx.x & 7, b = blockIdx.x >> 3;
  int n0 = pt << 7;
  int q = t >> 2, j = t & 3;
  int pql = q & 31;             // pixel-quad 0..31
  int chal = t >> 7;            // c-half 0/1
  int p0 = n0 + (pql << 2);
  const float* xb = x + (size_t)b * CIN * NPIX;
  short* xrow = xT + (size_t)((b << 10) + p0 + j) * 256;
  float s = 0.f, sq = 0.f;
  #pragma unroll
  for (int i = 0; i < 16; i++) {
    bf16x8 o;
    #pragma unroll
    for (int sub = 0; sub < 2; sub++) {
      int c0 = (i << 4) + (chal << 3) + (sub << 2);
      float4 v = *(const float4*)(xb + (size_t)(c0 + j) * NPIX + p0);
      float v0 = v.x, v1 = v.y, v2 = v.z, v3 = v.w;
      // 4x4 transpose across quad lanes (2 butterfly rounds).
      // Stage 1 (mask 1): even lane sends v1/v3, receives INTO v1/v3;
      //                   odd lane sends v0/v2, receives INTO v0/v2.
      float e0 = __shfl_xor((j & 1) ? v0 : v1, 1);
      float e1 = __shfl_xor((j & 1) ? v2 : v3, 1);
      if (j & 1) { v0 = e0; v2 = e1; } else { v1 = e0; v3 = e1; }
      // Stage 2 (mask 2): low lane sends v2/v3, receives INTO v2/v3;
      //                   high lane sends v0/v1, receives INTO v0/v1.
      float e2 = __shfl_xor((j & 2) ? v0 : v2, 2);
      float e3 = __shfl_xor((j & 2) ? v1 : v3, 2);
      if (j & 2) { v0 = e2; v1 = e3; } else { v2 = e2; v3 = e3; }
      s += v0 + v1 + v2 + v3;
      sq += v0 * v0 + v1 * v1 + v2 * v2 + v3 * v3;
      o[(sub << 2) + 0] = f2bf(v0);
      o[(sub << 2) + 1] = f2bf(v1);
      o[(sub << 2) + 2] = f2bf(v2);
      o[(sub << 2) + 3] = f2bf(v3);
    }
    *(bf16x8*)(xrow + (i << 4) + (chal << 3)) = o;
  }
  ps[chal][t & 127] = s;
  pq[chal][t & 127] = sq;
  __syncthreads();
  if (t < 128) {
    float ss = ps[0][t] + ps[1][t];
    float qq = pq[0][t] + pq[1][t];
    float m = ss * (1.f / 256.f);
    float var = qq * (1.f / 256.f) - m * m;
    int p = (b << 10) + n0 + t;
    mu[p] = m;
    rstd[p] = rsqrtf(var + EPSV);
  }
}

// ---------------- K1b: [k|v] GEMM from xT; k overwrites xT in-place ---------
// grid 512 = 64 b x 8 pixel-tiles(128). Block 256 (4 waves, 2x2 tiles).
// LN folded: k[p][d] = rstd_p*(acc_pd - mu_p*A_d) + B_d.
__global__ __launch_bounds__(256, 2) void kv_gemm(
    const short* __restrict__ xT,
    const float* __restrict__ mu, const float* __restrict__ rstd,
    const short* __restrict__ wkv,
    const float* __restrict__ kvA, const float* __restrict__ kvB,
    short* __restrict__ kout, short* __restrict__ vTout) {
  __shared__ __align__(16) short As[128 * BKA];
  __shared__ float mus[128], rss[128];
  int t = threadIdx.x;
  int pt = blockIdx.x & 7, b = blockIdx.x >> 3;
  int n0 = pt << 7;
  // stage A-tile: contiguous b128 copies. Row = 256 shorts = 32 x 8-short
  // chunks; 4096 chunks total -> p = idx>>5 (0..127), c8 = (idx&31)*8.
  const short* xtb = xT + (size_t)((b << 10) + n0) * 256;
  #pragma unroll
  for (int pass = 0; pass < 16; pass++) {
    int idx = (pass << 8) + t;          // 16B chunk id, 0..4095
    int p = idx >> 5, c8 = (idx & 31) << 3;
    bf16x8 v = *(const bf16x8*)(xtb + ((size_t)idx << 3));
    *(bf16x8*)&As[p * BKA + c8] = v;
  }
  if (t < 128) {
    mus[t] = mu[(b << 10) + n0 + t];
    rss[t] = rstd[(b << 10) + n0 + t];
  }
  __syncthreads();
  int w = t >> 6, lane = t & 63, quad = lane >> 4, lid = lane & 15;
  int wm = w & 1, wn = w >> 1;
  #pragma unroll
  for (int nt = 0; nt < 4; nt++) {
    f32x4 acc[4][4];
    #pragma unroll
    for (int i = 0; i < 4; i++)
      #pragma unroll
      for (int j = 0; j < 4; j++) acc[i][j] = 0.f;
    #pragma unroll
    for (int ks = 0; ks < 8; ks++) {
      int kof = (ks << 5) + (quad << 3);
      bf16x8 af[4], bfr[4];
      #pragma unroll
      for (int i = 0; i < 4; i++)
        af[i] = *(const bf16x8*)&As[(wm * 64 + i * 16 + lid) * BKA + kof];
      #pragma unroll
      for (int j = 0; j < 4; j++)
        bfr[j] = *(const bf16x8*)(wkv + (size_t)((nt << 7) + wn * 64 + j * 16 + lid) * 256 + kof);
      #pragma unroll
      for (int i = 0; i < 4; i++)
        #pragma unroll
        for (int j = 0; j < 4; j++)
          acc[i][j] = __builtin_amdgcn_mfma_f32_16x16x32_bf16(af[i], bfr[j], acc[i][j], 0, 0, 0);
    }
    #pragma unroll
    for (int i = 0; i < 4; i++) {
      int pl = wm * 64 + i * 16 + (quad << 2);     // local pixel row base
      #pragma unroll
      for (int j = 0; j < 4; j++) {
        int dim = (nt << 7) + wn * 64 + j * 16 + lid;
        float Ad = kvA[dim], Bd = kvB[dim];
        if (nt < 2) {
          #pragma unroll
          for (int r = 0; r < 4; r++) {
            float val = rss[pl + r] * (acc[i][j][r] - mus[pl + r] * Ad) + Bd;
            kout[((size_t)((b << 10) + n0 + pl + r)) * 256 + dim] = f2bf(val);
          }
        } else {
          short4 hv;
          hv.x = f2bf(rss[pl + 0] * (acc[i][j][0] - mus[pl + 0] * Ad) + Bd);
          hv.y = f2bf(rss[pl + 1] * (acc[i][j][1] - mus[pl + 1] * Ad) + Bd);
          hv.z = f2bf(rss[pl + 2] * (acc[i][j][2] - mus[pl + 2] * Ad) + Bd);
          hv.w = f2bf(rss[pl + 3] * (acc[i][j][3] - mus[pl + 3] * Ad) + Bd);
          *(short4*)(vTout + (size_t)b * 262144 + (size_t)(dim - 256) * 1024 + n0 + pl) = hv;
        }
      }
    }
  }
}

// ---------------- K3: slot init — slots = slots_mu, LN_s, q0 ----------------
__global__ __launch_bounds__(256) void slot_init(
    const float* __restrict__ slots_mu,
    const float* __restrict__ lsg, const float* __restrict__ lsb,
    const short* __restrict__ wq_b,
    float* __restrict__ slbuf, short* __restrict__ slbG, short* __restrict__ qb) {
  __shared__ float sl[8][256];
  __shared__ float mus[8], rss[8];
  __shared__ __align__(16) short slnb[8 * SP];
  int b = blockIdx.x, t = threadIdx.x;
  int wave = t >> 6, lane = t & 63, quad = lane >> 4, lid = lane & 15;
  int arow = (lid & 7) * SP, kof0 = quad << 3;
  for (int idx = t; idx < 2048; idx += 256) {
    float v = slots_mu[idx];
    sl[idx >> 8][idx & 255] = v;
    slbuf[(b << 11) + idx] = v;
    slbG[(b << 11) + idx] = f2bf(v);
  }
  __syncthreads();
  {
    int s0 = (wave << 1) + (lane >> 5);
    int l32 = lane & 31;
    float a0 = 0.f, a1 = 0.f;
    #pragma unroll
    for (int j = 0; j < 8; j++) { float v = sl[s0][l32 + (j << 5)]; a0 += v; a1 += v * v; }
    #pragma unroll
    for (int m = 1; m < 32; m <<= 1) { a0 += __shfl_xor(a0, m); a1 += __shfl_xor(a1, m); }
    if (l32 == 0) {
      float mn = a0 * (1.f / 256.f);
      float var = a1 * (1.f / 256.f) - mn * mn;
      mus[s0] = mn; rss[s0] = rsqrtf(var + EPSV);
    }
  }
  __syncthreads();
  for (int idx = t; idx < 2048; idx += 256) {
    int s = idx >> 8, c = idx & 255;
    slnb[s * SP + c] = f2bf((sl[s][c] - mus[s]) * rss[s] * lsg[c] + lsb[c]);
  }
  __syncthreads();
  #pragma unroll
  for (int nt = 0; nt < 4; nt++) {
    int d = (wave << 6) + (nt << 4) + lid;
    f32x4 qa = 0.f;
    #pragma unroll
    for (int ks = 0; ks < 8; ks++) {
      bf16x8 a = *(const bf16x8*)&slnb[arow + (ks << 5) + kof0];
      bf16x8 bb = *(const bf16x8*)(wq_b + (size_t)d * 256 + (ks << 5) + kof0);
      qa = __builtin_amdgcn_mfma_f32_16x16x32_bf16(a, bb, qa, 0, 0, 0);
    }
    #pragma unroll
    for (int r = 0; r < 4; r++) {
      int s = (quad << 2) + r;
      if (s < 8) qb[(b << 11) + (s << 8) + d] = f2bf(qa[r]);
    }
  }
}

// ---------------- K4: heavy — logits + softmax + partial updates ------------
// grid (16 chunks, 64 b), block 256. chunk = 64 pixels.
__global__ __launch_bounds__(256) void attn_heavy(
    const short* __restrict__ kbuf, const short* __restrict__ vT,
    const short* __restrict__ qb,
    short* __restrict__ partials, float* __restrict__ out_attn, int write_attn) {
  __shared__ __align__(16) short attT[8 * AP];
  int chunk = blockIdx.x, b = blockIdx.y;
  int t = threadIdx.x, wave = t >> 6, lane = t & 63, quad = lane >> 4, lid = lane & 15;
  int kof0 = quad << 3;
  bf16x8 qf[8];
  const short* qpb = qb + ((size_t)b << 11) + (lid & 7) * 256 + kof0;
  #pragma unroll
  for (int ks = 0; ks < 8; ks++) qf[ks] = *(const bf16x8*)(qpb + (ks << 5));
  {
    int p0l = wave << 4;
    const short* kb = kbuf + ((size_t)((b << 10) + (chunk << 6) + p0l + lid)) * 256 + kof0;
    f32x4 la = 0.f;
    #pragma unroll
    for (int ks = 0; ks < 8; ks++) {
      bf16x8 a = *(const bf16x8*)(kb + (ks << 5));
      la = __builtin_amdgcn_mfma_f32_16x16x32_bf16(a, qf[ks], la, 0, 0, 0);
    }
    #pragma unroll
    for (int r = 0; r < 4; r++) {
      float lg = la[r] * 0.0625f;
      float mx = lg;
      #pragma unroll
      for (int m = 1; m < 16; m <<= 1) mx = fmaxf(mx, __shfl_xor(mx, m));
      float e = __expf(lg - mx);
      float sm = e;
      #pragma unroll
      for (int m = 1; m < 16; m <<= 1) sm += __shfl_xor(sm, m);
      float at = (e + e) / sm;
      if (lid < 8) {
        int pl = p0l + (quad << 2) + r;
        attT[lid * AP + pl] = f2bf(at);
        if (write_attn) {
          int p = (chunk << 6) + pl;
          out_attn[((size_t)b << 13) + (p << 3) + lid] = at;
        }
      }
    }
  }
  __syncthreads();
  #pragma unroll
  for (int nt = 0; nt < 4; nt++) {
    int d0 = (wave << 6) + (nt << 4);
    f32x4 ua = 0.f;
    #pragma unroll
    for (int ks = 0; ks < 2; ks++) {
      bf16x8 a = *(const bf16x8*)&attT[(lid & 7) * AP + (ks << 5) + kof0];
      bf16x8 bb = *(const bf16x8*)(vT + (size_t)b * 262144 + (size_t)(d0 + lid) * 1024
                                   + (chunk << 6) + (ks << 5) + kof0);
      ua = __builtin_amdgcn_mfma_f32_16x16x32_bf16(a, bb, ua, 0, 0, 0);
    }
    #pragma unroll
    for (int r = 0; r < 4; r++) {
      int s = (quad << 2) + r;
      if (s < 8)
        partials[(((size_t)(b << 4) + chunk) << 11) + (s << 8) + d0 + lid] = f2bf(ua[r]);
    }
  }
}

// ---------------- K5: reduce partials + GRU + MLP + (LN_s + q next) ---------
__global__ __launch_bounds__(256) void slot_reduce(
    const short* __restrict__ partials,
    float* __restrict__ slbuf, short* __restrict__ slbG, short* __restrict__ qb,
    const short* __restrict__ wih_b, const short* __restrict__ whh_b,
    const float* __restrict__ bih, const float* __restrict__ bhh,
    const float* __restrict__ lmg, const float* __restrict__ lmb,
    const short* __restrict__ w1_b, const float* __restrict__ b1,
    const short* __restrict__ w2_b, const float* __restrict__ b2,
    const float* __restrict__ lsg, const float* __restrict__ lsb,
    const short* __restrict__ wq_b,
    float* __restrict__ out, int last) {
  __shared__ float sl[8][256];
  __shared__ float mus[8], rss[8];
  __shared__ __align__(16) short updb[8 * SP], slb_l[8 * SP], lnmb[8 * SP],
                                  hmb[8 * SP], slnb[8 * SP];
  int b = blockIdx.x, t = threadIdx.x;
  int wave = t >> 6, lane = t & 63, quad = lane >> 4, lid = lane & 15;
  int arow = (lid & 7) * SP, kof0 = quad << 3;
  for (int idx = t; idx < 2048; idx += 256) {
    float sum = 0.f;
    #pragma unroll
    for (int c = 0; c < 16; c++) sum += b2f(partials[(((size_t)(b << 4) + c) << 11) + idx]);
    int s = idx >> 8, dd = idx & 255;
    updb[s * SP + dd] = f2bf(sum);
    sl[s][dd] = slbuf[(b << 11) + idx];
    slb_l[s * SP + dd] = slbG[(b << 11) + idx];
  }
  __syncthreads();
  #pragma unroll
  for (int nt = 0; nt < 4; nt++) {
    int d = (wave << 6) + (nt << 4) + lid;
    f32x4 gi[3], gh[3];
    #pragma unroll
    for (int g = 0; g < 3; g++) { gi[g] = 0.f; gh[g] = 0.f; }
    #pragma unroll
    for (int ks = 0; ks < 8; ks++) {
      bf16x8 au  = *(const bf16x8*)&updb [arow + (ks << 5) + kof0];
      bf16x8 as2 = *(const bf16x8*)&slb_l[arow + (ks << 5) + kof0];
      #pragma unroll
      for (int g = 0; g < 3; g++) {
        bf16x8 bi = *(const bf16x8*)(wih_b + (size_t)((g << 8) + d) * 256 + (ks << 5) + kof0);
        bf16x8 bh = *(const bf16x8*)(whh_b + (size_t)((g << 8) + d) * 256 + (ks << 5) + kof0);
        gi[g] = __builtin_amdgcn_mfma_f32_16x16x32_bf16(au,  bi, gi[g], 0, 0, 0);
        gh[g] = __builtin_amdgcn_mfma_f32_16x16x32_bf16(as2, bh, gh[g], 0, 0, 0);
      }
    }
    float bi0 = bih[d], bi1 = bih[256 + d], bi2 = bih[512 + d];
    float bh0 = bhh[d], bh1 = bhh[256 + d], bh2 = bhh[512 + d];
    #pragma unroll
    for (int r = 0; r < 4; r++) {
      int s = (quad << 2) + r;
      if (s < 8) {
        float rg = 1.f / (1.f + __expf(-(gi[0][r] + bi0 + gh[0][r] + bh0)));
        float zg = 1.f / (1.f + __expf(-(gi[1][r] + bi1 + gh[1][r] + bh1)));
        float ng = tanhf(gi[2][r] + bi2 + rg * (gh[2][r] + bh2));
        sl[s][d] = (1.f - zg) * ng + zg * sl[s][d];
      }
    }
  }
  __syncthreads();
  {
    int s0 = (wave << 1) + (lane >> 5);
    int l32 = lane & 31;
    float a0 = 0.f, a1 = 0.f;
    #pragma unroll
    for (int j = 0; j < 8; j++) { float v = sl[s0][l32 + (j << 5)]; a0 += v; a1 += v * v; }
    #pragma unroll
    for (int m = 1; m < 32; m <<= 1) { a0 += __shfl_xor(a0, m); a1 += __shfl_xor(a1, m); }
    if (l32 == 0) {
      float mn = a0 * (1.f / 256.f);
      float var = a1 * (1.f / 256.f) - mn * mn;
      mus[s0] = mn; rss[s0] = rsqrtf(var + EPSV);
    }
  }
  __syncthreads();
  for (int idx = t; idx < 2048; idx += 256) {
    int s = idx >> 8, c = idx & 255;
    lnmb[s * SP + c] = f2bf((sl[s][c] - mus[s]) * rss[s] * lmg[c] + lmb[c]);
  }
  __syncthreads();
  #pragma unroll
  for (int nt = 0; nt < 4; nt++) {
    int d = (wave << 6) + (nt << 4) + lid;
    f32x4 ha = 0.f;
    #pragma unroll
    for (int ks = 0; ks < 8; ks++) {
      bf16x8 a = *(const bf16x8*)&lnmb[arow + (ks << 5) + kof0];
      bf16x8 bb = *(const bf16x8*)(w1_b + (size_t)d * 256 + (ks << 5) + kof0);
      ha = __builtin_amdgcn_mfma_f32_16x16x32_bf16(a, bb, ha, 0, 0, 0);
    }
    float bb1 = b1[d];
    #pragma unroll
    for (int r = 0; r < 4; r++) {
      int s = (quad << 2) + r;
      if (s < 8) hmb[s * SP + d] = f2bf(fmaxf(ha[r] + bb1, 0.f));
    }
  }
  __syncthreads();
  #pragma unroll
  for (int nt = 0; nt < 4; nt++) {
    int d = (wave << 6) + (nt << 4) + lid;
    f32x4 oa = 0.f;
    #pragma unroll
    for (int ks = 0; ks < 8; ks++) {
      bf16x8 a = *(const bf16x8*)&hmb[arow + (ks << 5) + kof0];
      bf16x8 bb = *(const bf16x8*)(w2_b + (size_t)d * 256 + (ks << 5) + kof0);
      oa = __builtin_amdgcn_mfma_f32_16x16x32_bf16(a, bb, oa, 0, 0, 0);
    }
    float bb2 = b2[d];
    #pragma unroll
    for (int r = 0; r < 4; r++) {
      int s = (quad << 2) + r;
      if (s < 8) sl[s][d] = sl[s][d] + oa[r] + bb2;
    }
  }
  __syncthreads();
  if (last) {
    for (int idx = t; idx < 2048; idx += 256)
      out[(b << 11) + idx] = sl[idx >> 8][idx & 255];
    return;
  }
  for (int idx = t; idx < 2048; idx += 256) {
    float v = sl[idx >> 8][idx & 255];
    slbuf[(b << 11) + idx] = v;
    slbG[(b << 11) + idx] = f2bf(v);
  }
  {
    int s0 = (wave << 1) + (lane >> 5);
    int l32 = lane & 31;
    float a0 = 0.f, a1 = 0.f;
    #pragma unroll
    for (int j = 0; j < 8; j++) { float v = sl[s0][l32 + (j << 5)]; a0 += v; a1 += v * v; }
    #pragma unroll
    for (int m = 1; m < 32; m <<= 1) { a0 += __shfl_xor(a0, m); a1 += __shfl_xor(a1, m); }
    if (l32 == 0) {
      float mn = a0 * (1.f / 256.f);
      float var = a1 * (1.f / 256.f) - mn * mn;
      mus[s0] = mn; rss[s0] = rsqrtf(var + EPSV);
    }
  }
  __syncthreads();
  for (int idx = t; idx < 2048; idx += 256) {
    int s = idx >> 8, c = idx & 255;
    slnb[s * SP + c] = f2bf((sl[s][c] - mus[s]) * rss[s] * lsg[c] + lsb[c]);
  }
  __syncthreads();
  #pragma unroll
  for (int nt = 0; nt < 4; nt++) {
    int d = (wave << 6) + (nt << 4) + lid;
    f32x4 qa = 0.f;
    #pragma unroll
    for (int ks = 0; ks < 8; ks++) {
      bf16x8 a = *(const bf16x8*)&slnb[arow + (ks << 5) + kof0];
      bf16x8 bb = *(const bf16x8*)(wq_b + (size_t)d * 256 + (ks << 5) + kof0);
      qa = __builtin_amdgcn_mfma_f32_16x16x32_bf16(a, bb, qa, 0, 0, 0);
    }
    #pragma unroll
    for (int r = 0; r < 4; r++) {
      int s = (quad << 2) + r;
      if (s < 8) qb[(b << 11) + (s << 8) + d] = f2bf(qa[r]);
    }
  }
}

extern "C" void kernel_launch(void* const* d_in, const int* in_sizes, int n_in,
                              void* d_out, int out_size, void* d_ws, size_t ws_size,
                              hipStream_t stream) {
  const float* x        = (const float*)d_in[0];
  const float* slots_mu = (const float*)d_in[1];
  const float* ln_in_g  = (const float*)d_in[2];
  const float* ln_in_b  = (const float*)d_in[3];
  const float* wk       = (const float*)d_in[4];
  const float* wv       = (const float*)d_in[5];
  const float* ln_s_g   = (const float*)d_in[6];
  const float* ln_s_b   = (const float*)d_in[7];
  const float* wq       = (const float*)d_in[8];
  const float* wih      = (const float*)d_in[9];
  const float* whh      = (const float*)d_in[10];
  const float* bih      = (const float*)d_in[11];
  const float* bhh      = (const float*)d_in[12];
  const float* lmg      = (const float*)d_in[13];
  const float* lmb      = (const float*)d_in[14];
  const float* w1       = (const float*)d_in[15];
  const float* b1       = (const float*)d_in[16];
  const float* w2       = (const float*)d_in[17];
  const float* b2       = (const float*)d_in[18];
  float* out = (float*)d_out;
  float* out_attn = out + 131072;

  char* ws = (char*)d_ws;
  short* kbuf   = (short*)(ws);                  // 33,554,432 (xT then k in-place)
  short* vT     = (short*)(ws + 33554432);       // 33,554,432
  short* wkv_b  = (short*)(ws + 67108864);       //    262,144
  short* wq_b   = (short*)(ws + 67371008);       //    131,072
  short* wih_b  = (short*)(ws + 67502080);       //    393,216
  short* whh_b  = (short*)(ws + 67895296);       //    393,216
  short* w1_b   = (short*)(ws + 68288512);       //    131,072
  short* w2_b   = (short*)(ws + 68419584);       //    131,072
  float* slbuf  = (float*)(ws + 68550656);       //    524,288
  short* slbG   = (short*)(ws + 69074944);       //    262,144
  short* qb     = (short*)(ws + 69337088);       //    262,144
  short* parts  = (short*)(ws + 69599232);       //  4,194,304
  float* kvA    = (float*)(ws + 73793536);       //      2,048
  float* kvB    = (float*)(ws + 73795584);       //      2,048
  float* muB    = (float*)(ws + 73797632);       //    262,144
  float* rstdB  = (float*)(ws + 74059776);       //    262,144 -> 74,321,920

  wcvt<<<2304, 256, 0, stream>>>(wq, wih, whh, w1, w2,
                                 wq_b, wih_b, whh_b, w1_b, w2_b);
  wfold<<<512, 256, 0, stream>>>(wk, wv, ln_in_g, ln_in_b, wkv_b, kvA, kvB);
  xt_stats<<<512, 256, 0, stream>>>(x, kbuf, muB, rstdB);
  kv_gemm<<<512, 256, 0, stream>>>(kbuf, muB, rstdB, wkv_b, kvA, kvB, kbuf, vT);
  slot_init<<<64, 256, 0, stream>>>(slots_mu, ln_s_g, ln_s_b, wq_b, slbuf, slbG, qb);
  for (int it = 0; it < 3; it++) {
    attn_heavy<<<dim3(16, 64), 256, 0, stream>>>(kbuf, vT, qb, parts, out_attn,
                                                 (it == 2) ? 1 : 0);
    slot_reduce<<<64, 256, 0, stream>>>(parts, slbuf, slbG, qb,
                                        wih_b, whh_b, bih, bhh, lmg, lmb,
                                        w1_b, b1, w2_b, b2, ln_s_g, ln_s_b, wq_b,
                                        out, (it == 2) ? 1 : 0);
  }
}

// Round 7
// 361.405 us; speedup vs baseline: 1.0922x; 1.0922x over previous
//
#include <hip/hip_runtime.h>

#define NPIX 1024
#define CIN  256
#define EPSV 1e-5f
#define SP 264
#define AP 72
#define BKA 264

typedef __attribute__((ext_vector_type(8))) short bf16x8;
typedef __attribute__((ext_vector_type(4))) float f32x4;

__device__ __forceinline__ short f2bf(float f) {
  unsigned u = __float_as_uint(f);
  unsigned r = (u + 0x7FFFu + ((u >> 16) & 1u)) >> 16;
  return (short)r;
}
__device__ __forceinline__ float b2f(short s) {
  return __uint_as_float(((unsigned)(unsigned short)s) << 16);
}

// ---------------- K0a: non-kv weights fp32 -> bf16 --------------------------
__global__ __launch_bounds__(256) void wcvt(
    const float* __restrict__ wq, const float* __restrict__ wih,
    const float* __restrict__ whh, const float* __restrict__ w1,
    const float* __restrict__ w2,
    short* __restrict__ wq_b, short* __restrict__ wih_b, short* __restrict__ whh_b,
    short* __restrict__ w1_b, short* __restrict__ w2_b) {
  int id = blockIdx.x * 256 + threadIdx.x;
  if      (id <  65536) wq_b [id         ] = f2bf(wq [id         ]);
  else if (id < 262144) wih_b[id -  65536] = f2bf(wih[id -  65536]);
  else if (id < 458752) whh_b[id - 262144] = f2bf(whh[id - 262144]);
  else if (id < 524288) w1_b [id - 458752] = f2bf(w1 [id - 458752]);
  else if (id < 589824) w2_b [id - 524288] = f2bf(w2 [id - 524288]);
}

// ---------------- K0b: wkv' = g*w (bf16) + A=sum(g*w), B=sum(b*w) -----------
__global__ __launch_bounds__(256) void wfold(
    const float* __restrict__ wk, const float* __restrict__ wv,
    const float* __restrict__ g, const float* __restrict__ bet,
    short* __restrict__ wkv_b, float* __restrict__ kvA, float* __restrict__ kvB) {
  __shared__ float ra[4], rb[4];
  int d = blockIdx.x;                 // 0..511
  int t = threadIdx.x;
  const float* wrow = (d < 256) ? (wk + (size_t)d * 256) : (wv + (size_t)(d - 256) * 256);
  float w = wrow[t], gg = g[t], bb = bet[t];
  float pa = gg * w, pb = bb * w;
  wkv_b[(size_t)d * 256 + t] = f2bf(pa);
  #pragma unroll
  for (int m = 1; m < 64; m <<= 1) { pa += __shfl_xor(pa, m); pb += __shfl_xor(pb, m); }
  int wave = t >> 6, lane = t & 63;
  if (lane == 0) { ra[wave] = pa; rb[wave] = pb; }
  __syncthreads();
  if (t == 0) {
    kvA[d] = ra[0] + ra[1] + ra[2] + ra[3];
    kvB[d] = rb[0] + rb[1] + rb[2] + rb[3];
  }
}

// ---------------- K1a: transpose x -> xT bf16 + LN stats --------------------
__global__ __launch_bounds__(256) void xt_stats(
    const float* __restrict__ x, short* __restrict__ xT,
    float* __restrict__ mu, float* __restrict__ rstd) {
  __shared__ float ps[2][128], pq[2][128];
  int t = threadIdx.x;
  int pt = blockIdx.x & 7, b = blockIdx.x >> 3;
  int n0 = pt << 7;
  int q = t >> 2, j = t & 3;
  int pql = q & 31;
  int chal = t >> 7;
  int p0 = n0 + (pql << 2);
  const float* xb = x + (size_t)b * CIN * NPIX;
  short* xrow = xT + (size_t)((b << 10) + p0 + j) * 256;
  float s = 0.f, sq = 0.f;
  #pragma unroll
  for (int i = 0; i < 16; i++) {
    bf16x8 o;
    #pragma unroll
    for (int sub = 0; sub < 2; sub++) {
      int c0 = (i << 4) + (chal << 3) + (sub << 2);
      float4 v = *(const float4*)(xb + (size_t)(c0 + j) * NPIX + p0);
      float v0 = v.x, v1 = v.y, v2 = v.z, v3 = v.w;
      float e0 = __shfl_xor((j & 1) ? v0 : v1, 1);
      float e1 = __shfl_xor((j & 1) ? v2 : v3, 1);
      if (j & 1) { v0 = e0; v2 = e1; } else { v1 = e0; v3 = e1; }
      float e2 = __shfl_xor((j & 2) ? v0 : v2, 2);
      float e3 = __shfl_xor((j & 2) ? v1 : v3, 2);
      if (j & 2) { v0 = e2; v1 = e3; } else { v2 = e2; v3 = e3; }
      s += v0 + v1 + v2 + v3;
      sq += v0 * v0 + v1 * v1 + v2 * v2 + v3 * v3;
      o[(sub << 2) + 0] = f2bf(v0);
      o[(sub << 2) + 1] = f2bf(v1);
      o[(sub << 2) + 2] = f2bf(v2);
      o[(sub << 2) + 3] = f2bf(v3);
    }
    *(bf16x8*)(xrow + (i << 4) + (chal << 3)) = o;
  }
  ps[chal][t & 127] = s;
  pq[chal][t & 127] = sq;
  __syncthreads();
  if (t < 128) {
    float ss = ps[0][t] + ps[1][t];
    float qq = pq[0][t] + pq[1][t];
    float m = ss * (1.f / 256.f);
    float var = qq * (1.f / 256.f) - m * m;
    int p = (b << 10) + n0 + t;
    mu[p] = m;
    rstd[p] = rsqrtf(var + EPSV);
  }
}

// ---------------- K1b: [k|v] GEMM from xT; k overwrites xT in-place ---------
__global__ __launch_bounds__(256, 2) void kv_gemm(
    const short* __restrict__ xT,
    const float* __restrict__ mu, const float* __restrict__ rstd,
    const short* __restrict__ wkv,
    const float* __restrict__ kvA, const float* __restrict__ kvB,
    short* __restrict__ kout, short* __restrict__ vTout) {
  __shared__ __align__(16) short As[128 * BKA];
  __shared__ float mus[128], rss[128];
  int t = threadIdx.x;
  int pt = blockIdx.x & 7, b = blockIdx.x >> 3;
  int n0 = pt << 7;
  const short* xtb = xT + (size_t)((b << 10) + n0) * 256;
  #pragma unroll
  for (int pass = 0; pass < 16; pass++) {
    int idx = (pass << 8) + t;          // 16B chunk id, 0..4095
    int p = idx >> 5, c8 = (idx & 31) << 3;
    bf16x8 v = *(const bf16x8*)(xtb + ((size_t)idx << 3));
    *(bf16x8*)&As[p * BKA + c8] = v;
  }
  if (t < 128) {
    mus[t] = mu[(b << 10) + n0 + t];
    rss[t] = rstd[(b << 10) + n0 + t];
  }
  __syncthreads();
  int w = t >> 6, lane = t & 63, quad = lane >> 4, lid = lane & 15;
  int wm = w & 1, wn = w >> 1;
  #pragma unroll
  for (int nt = 0; nt < 4; nt++) {
    f32x4 acc[4][4];
    #pragma unroll
    for (int i = 0; i < 4; i++)
      #pragma unroll
      for (int j = 0; j < 4; j++) acc[i][j] = 0.f;
    #pragma unroll
    for (int ks = 0; ks < 8; ks++) {
      int kof = (ks << 5) + (quad << 3);
      bf16x8 af[4], bfr[4];
      #pragma unroll
      for (int i = 0; i < 4; i++)
        af[i] = *(const bf16x8*)&As[(wm * 64 + i * 16 + lid) * BKA + kof];
      #pragma unroll
      for (int j = 0; j < 4; j++)
        bfr[j] = *(const bf16x8*)(wkv + (size_t)((nt << 7) + wn * 64 + j * 16 + lid) * 256 + kof);
      #pragma unroll
      for (int i = 0; i < 4; i++)
        #pragma unroll
        for (int j = 0; j < 4; j++)
          acc[i][j] = __builtin_amdgcn_mfma_f32_16x16x32_bf16(af[i], bfr[j], acc[i][j], 0, 0, 0);
    }
    #pragma unroll
    for (int i = 0; i < 4; i++) {
      int pl = wm * 64 + i * 16 + (quad << 2);
      #pragma unroll
      for (int j = 0; j < 4; j++) {
        int dim = (nt << 7) + wn * 64 + j * 16 + lid;
        float Ad = kvA[dim], Bd = kvB[dim];
        if (nt < 2) {
          #pragma unroll
          for (int r = 0; r < 4; r++) {
            float val = rss[pl + r] * (acc[i][j][r] - mus[pl + r] * Ad) + Bd;
            kout[((size_t)((b << 10) + n0 + pl + r)) * 256 + dim] = f2bf(val);
          }
        } else {
          short4 hv;
          hv.x = f2bf(rss[pl + 0] * (acc[i][j][0] - mus[pl + 0] * Ad) + Bd);
          hv.y = f2bf(rss[pl + 1] * (acc[i][j][1] - mus[pl + 1] * Ad) + Bd);
          hv.z = f2bf(rss[pl + 2] * (acc[i][j][2] - mus[pl + 2] * Ad) + Bd);
          hv.w = f2bf(rss[pl + 3] * (acc[i][j][3] - mus[pl + 3] * Ad) + Bd);
          *(short4*)(vTout + (size_t)b * 262144 + (size_t)(dim - 256) * 1024 + n0 + pl) = hv;
        }
      }
    }
  }
}

// ---------------- K3: slot init — slots = slots_mu, LN_s, q0 ----------------
__global__ __launch_bounds__(256) void slot_init(
    const float* __restrict__ slots_mu,
    const float* __restrict__ lsg, const float* __restrict__ lsb,
    const short* __restrict__ wq_b,
    float* __restrict__ slbuf, short* __restrict__ slbG, short* __restrict__ qb) {
  __shared__ float sl[8][256];
  __shared__ float mus[8], rss[8];
  __shared__ __align__(16) short slnb[8 * SP];
  int b = blockIdx.x, t = threadIdx.x;
  int wave = t >> 6, lane = t & 63, quad = lane >> 4, lid = lane & 15;
  int arow = (lid & 7) * SP, kof0 = quad << 3;
  for (int idx = t; idx < 2048; idx += 256) {
    float v = slots_mu[idx];
    sl[idx >> 8][idx & 255] = v;
    slbuf[(b << 11) + idx] = v;
    slbG[(b << 11) + idx] = f2bf(v);
  }
  __syncthreads();
  {
    int s0 = (wave << 1) + (lane >> 5);
    int l32 = lane & 31;
    float a0 = 0.f, a1 = 0.f;
    #pragma unroll
    for (int j = 0; j < 8; j++) { float v = sl[s0][l32 + (j << 5)]; a0 += v; a1 += v * v; }
    #pragma unroll
    for (int m = 1; m < 32; m <<= 1) { a0 += __shfl_xor(a0, m); a1 += __shfl_xor(a1, m); }
    if (l32 == 0) {
      float mn = a0 * (1.f / 256.f);
      float var = a1 * (1.f / 256.f) - mn * mn;
      mus[s0] = mn; rss[s0] = rsqrtf(var + EPSV);
    }
  }
  __syncthreads();
  for (int idx = t; idx < 2048; idx += 256) {
    int s = idx >> 8, c = idx & 255;
    slnb[s * SP + c] = f2bf((sl[s][c] - mus[s]) * rss[s] * lsg[c] + lsb[c]);
  }
  __syncthreads();
  #pragma unroll
  for (int nt = 0; nt < 4; nt++) {
    int d = (wave << 6) + (nt << 4) + lid;
    f32x4 qa = 0.f;
    #pragma unroll
    for (int ks = 0; ks < 8; ks++) {
      bf16x8 a = *(const bf16x8*)&slnb[arow + (ks << 5) + kof0];
      bf16x8 bb = *(const bf16x8*)(wq_b + (size_t)d * 256 + (ks << 5) + kof0);
      qa = __builtin_amdgcn_mfma_f32_16x16x32_bf16(a, bb, qa, 0, 0, 0);
    }
    #pragma unroll
    for (int r = 0; r < 4; r++) {
      int s = (quad << 2) + r;
      if (s < 8) qb[(b << 11) + (s << 8) + d] = f2bf(qa[r]);
    }
  }
}

// ---------------- K4: heavy — logits + softmax + partial updates ------------
__global__ __launch_bounds__(256) void attn_heavy(
    const short* __restrict__ kbuf, const short* __restrict__ vT,
    const short* __restrict__ qb,
    short* __restrict__ partials, float* __restrict__ out_attn, int write_attn) {
  __shared__ __align__(16) short attT[8 * AP];
  int chunk = blockIdx.x, b = blockIdx.y;
  int t = threadIdx.x, wave = t >> 6, lane = t & 63, quad = lane >> 4, lid = lane & 15;
  int kof0 = quad << 3;
  bf16x8 qf[8];
  const short* qpb = qb + ((size_t)b << 11) + (lid & 7) * 256 + kof0;
  #pragma unroll
  for (int ks = 0; ks < 8; ks++) qf[ks] = *(const bf16x8*)(qpb + (ks << 5));
  {
    int p0l = wave << 4;
    const short* kb = kbuf + ((size_t)((b << 10) + (chunk << 6) + p0l + lid)) * 256 + kof0;
    f32x4 la = 0.f;
    #pragma unroll
    for (int ks = 0; ks < 8; ks++) {
      bf16x8 a = *(const bf16x8*)(kb + (ks << 5));
      la = __builtin_amdgcn_mfma_f32_16x16x32_bf16(a, qf[ks], la, 0, 0, 0);
    }
    #pragma unroll
    for (int r = 0; r < 4; r++) {
      float lg = la[r] * 0.0625f;
      float mx = lg;
      #pragma unroll
      for (int m = 1; m < 16; m <<= 1) mx = fmaxf(mx, __shfl_xor(mx, m));
      float e = __expf(lg - mx);
      float sm = e;
      #pragma unroll
      for (int m = 1; m < 16; m <<= 1) sm += __shfl_xor(sm, m);
      float at = (e + e) / sm;
      if (lid < 8) {
        int pl = p0l + (quad << 2) + r;
        attT[lid * AP + pl] = f2bf(at);
        if (write_attn) {
          int p = (chunk << 6) + pl;
          out_attn[((size_t)b << 13) + (p << 3) + lid] = at;
        }
      }
    }
  }
  __syncthreads();
  #pragma unroll
  for (int nt = 0; nt < 4; nt++) {
    int d0 = (wave << 6) + (nt << 4);
    f32x4 ua = 0.f;
    #pragma unroll
    for (int ks = 0; ks < 2; ks++) {
      bf16x8 a = *(const bf16x8*)&attT[(lid & 7) * AP + (ks << 5) + kof0];
      bf16x8 bb = *(const bf16x8*)(vT + (size_t)b * 262144 + (size_t)(d0 + lid) * 1024
                                   + (chunk << 6) + (ks << 5) + kof0);
      ua = __builtin_amdgcn_mfma_f32_16x16x32_bf16(a, bb, ua, 0, 0, 0);
    }
    #pragma unroll
    for (int r = 0; r < 4; r++) {
      int s = (quad << 2) + r;
      if (s < 8)
        partials[(((size_t)(b << 4) + chunk) << 11) + (s << 8) + d0 + lid] = f2bf(ua[r]);
    }
  }
}

// ---------------- K5: reduce + GRU + MLP + (LN_s + q next), block=1024 ------
// 16 waves; wave w owns output columns d = w*16+lid for every GEMM stage.
// GRU: one wave computes all 6 gate GEMMs for its columns in registers.
__global__ __launch_bounds__(1024) void slot_reduce(
    const short* __restrict__ partials,
    float* __restrict__ slbuf, short* __restrict__ slbG, short* __restrict__ qb,
    const short* __restrict__ wih_b, const short* __restrict__ whh_b,
    const float* __restrict__ bih, const float* __restrict__ bhh,
    const float* __restrict__ lmg, const float* __restrict__ lmb,
    const short* __restrict__ w1_b, const float* __restrict__ b1,
    const short* __restrict__ w2_b, const float* __restrict__ b2,
    const float* __restrict__ lsg, const float* __restrict__ lsb,
    const short* __restrict__ wq_b,
    float* __restrict__ out, int last) {
  __shared__ float sl[8][256];
  __shared__ float mus[8], rss[8];
  __shared__ __align__(16) short updb[8 * SP], slb_l[8 * SP], lnmb[8 * SP],
                                  hmb[8 * SP], slnb[8 * SP];
  int b = blockIdx.x, t = threadIdx.x;
  int wave = t >> 6, lane = t & 63, quad = lane >> 4, lid = lane & 15;
  int arow = (lid & 7) * SP, kof0 = quad << 3;
  int d = (wave << 4) + lid;                 // this wave's output column
  // ---- stage 0: vectorized partial reduce + slot staging (split by thread)
  if (t < 256) {
    int s = t >> 5, d8 = (t & 31) << 3;
    float acc[8];
    #pragma unroll
    for (int i = 0; i < 8; i++) acc[i] = 0.f;
    #pragma unroll
    for (int c = 0; c < 16; c++) {
      bf16x8 v = *(const bf16x8*)(partials + ((((size_t)(b << 4) + c) << 11) + (s << 8) + d8));
      #pragma unroll
      for (int i = 0; i < 8; i++) acc[i] += b2f(v[i]);
    }
    bf16x8 o;
    #pragma unroll
    for (int i = 0; i < 8; i++) o[i] = f2bf(acc[i]);
    *(bf16x8*)&updb[s * SP + d8] = o;
  } else if (t < 512) {
    int tt = t - 256;
    int s = tt >> 5, d8 = (tt & 31) << 3;
    bf16x8 v = *(const bf16x8*)(slbG + ((b << 11) + (s << 8) + d8));
    *(bf16x8*)&slb_l[s * SP + d8] = v;
  } else if (t < 768) {
    int tt = t - 512;
    int s = tt >> 5, d8 = (tt & 31) << 3;
    float4 v0 = *(const float4*)(slbuf + ((b << 11) + (s << 8) + d8));
    float4 v1 = *(const float4*)(slbuf + ((b << 11) + (s << 8) + d8 + 4));
    *(float4*)&sl[s][d8] = v0;
    *(float4*)&sl[s][d8 + 4] = v1;
  }
  __syncthreads();
  // ---- stage 1: GRU — all 6 gate GEMMs for this wave's 16 columns
  {
    f32x4 gi0 = 0.f, gi1 = 0.f, gi2 = 0.f, gh0 = 0.f, gh1 = 0.f, gh2 = 0.f;
    #pragma unroll
    for (int ks = 0; ks < 8; ks++) {
      int kof = (ks << 5) + kof0;
      bf16x8 au = *(const bf16x8*)&updb [arow + kof];
      bf16x8 ah = *(const bf16x8*)&slb_l[arow + kof];
      bf16x8 w0 = *(const bf16x8*)(wih_b + (size_t)(0 * 256 + d) * 256 + kof);
      bf16x8 w1r = *(const bf16x8*)(wih_b + (size_t)(1 * 256 + d) * 256 + kof);
      bf16x8 w2r = *(const bf16x8*)(wih_b + (size_t)(2 * 256 + d) * 256 + kof);
      bf16x8 u0 = *(const bf16x8*)(whh_b + (size_t)(0 * 256 + d) * 256 + kof);
      bf16x8 u1 = *(const bf16x8*)(whh_b + (size_t)(1 * 256 + d) * 256 + kof);
      bf16x8 u2 = *(const bf16x8*)(whh_b + (size_t)(2 * 256 + d) * 256 + kof);
      gi0 = __builtin_amdgcn_mfma_f32_16x16x32_bf16(au, w0, gi0, 0, 0, 0);
      gi1 = __builtin_amdgcn_mfma_f32_16x16x32_bf16(au, w1r, gi1, 0, 0, 0);
      gi2 = __builtin_amdgcn_mfma_f32_16x16x32_bf16(au, w2r, gi2, 0, 0, 0);
      gh0 = __builtin_amdgcn_mfma_f32_16x16x32_bf16(ah, u0, gh0, 0, 0, 0);
      gh1 = __builtin_amdgcn_mfma_f32_16x16x32_bf16(ah, u1, gh1, 0, 0, 0);
      gh2 = __builtin_amdgcn_mfma_f32_16x16x32_bf16(ah, u2, gh2, 0, 0, 0);
    }
    float bi0 = bih[d], bi1 = bih[256 + d], bi2 = bih[512 + d];
    float bh0 = bhh[d], bh1 = bhh[256 + d], bh2 = bhh[512 + d];
    #pragma unroll
    for (int r = 0; r < 4; r++) {
      int s = (quad << 2) + r;
      if (s < 8) {
        float rg = 1.f / (1.f + __expf(-(gi0[r] + bi0 + gh0[r] + bh0)));
        float zg = 1.f / (1.f + __expf(-(gi1[r] + bi1 + gh1[r] + bh1)));
        float ng = tanhf(gi2[r] + bi2 + rg * (gh2[r] + bh2));
        sl[s][d] = (1.f - zg) * ng + zg * sl[s][d];   // owner-exclusive (s,d)
      }
    }
  }
  __syncthreads();
  // ---- stage 2: LN_m stats (wave per slot)
  if (wave < 8) {
    float a0 = 0.f, a1 = 0.f;
    #pragma unroll
    for (int j = 0; j < 4; j++) { float v = sl[wave][lane + (j << 6)]; a0 += v; a1 += v * v; }
    #pragma unroll
    for (int m = 1; m < 64; m <<= 1) { a0 += __shfl_xor(a0, m); a1 += __shfl_xor(a1, m); }
    if (lane == 0) {
      float mn = a0 * (1.f / 256.f);
      float var = a1 * (1.f / 256.f) - mn * mn;
      mus[wave] = mn; rss[wave] = rsqrtf(var + EPSV);
    }
  }
  __syncthreads();
  for (int idx = t; idx < 2048; idx += 1024) {
    int s = idx >> 8, c = idx & 255;
    lnmb[s * SP + c] = f2bf((sl[s][c] - mus[s]) * rss[s] * lmg[c] + lmb[c]);
  }
  __syncthreads();
  // ---- stage 3: MLP layer 1 (16 waves, one n-tile each)
  {
    f32x4 ha = 0.f;
    #pragma unroll
    for (int ks = 0; ks < 8; ks++) {
      int kof = (ks << 5) + kof0;
      bf16x8 a = *(const bf16x8*)&lnmb[arow + kof];
      bf16x8 bb = *(const bf16x8*)(w1_b + (size_t)d * 256 + kof);
      ha = __builtin_amdgcn_mfma_f32_16x16x32_bf16(a, bb, ha, 0, 0, 0);
    }
    float bb1 = b1[d];
    #pragma unroll
    for (int r = 0; r < 4; r++) {
      int s = (quad << 2) + r;
      if (s < 8) hmb[s * SP + d] = f2bf(fmaxf(ha[r] + bb1, 0.f));
    }
  }
  __syncthreads();
  // ---- stage 4: MLP layer 2 + residual
  {
    f32x4 oa = 0.f;
    #pragma unroll
    for (int ks = 0; ks < 8; ks++) {
      int kof = (ks << 5) + kof0;
      bf16x8 a = *(const bf16x8*)&hmb[arow + kof];
      bf16x8 bb = *(const bf16x8*)(w2_b + (size_t)d * 256 + kof);
      oa = __builtin_amdgcn_mfma_f32_16x16x32_bf16(a, bb, oa, 0, 0, 0);
    }
    float bb2 = b2[d];
    #pragma unroll
    for (int r = 0; r < 4; r++) {
      int s = (quad << 2) + r;
      if (s < 8) sl[s][d] = sl[s][d] + oa[r] + bb2;
    }
  }
  __syncthreads();
  if (last) {
    for (int idx = t; idx < 2048; idx += 1024)
      out[(b << 11) + idx] = sl[idx >> 8][idx & 255];
    return;
  }
  // ---- stage 5: persist slots; LN_s + q for next iteration
  for (int idx = t; idx < 2048; idx += 1024) {
    float v = sl[idx >> 8][idx & 255];
    slbuf[(b << 11) + idx] = v;
    slbG[(b << 11) + idx] = f2bf(v);
  }
  if (wave < 8) {
    float a0 = 0.f, a1 = 0.f;
    #pragma unroll
    for (int j = 0; j < 4; j++) { float v = sl[wave][lane + (j << 6)]; a0 += v; a1 += v * v; }
    #pragma unroll
    for (int m = 1; m < 64; m <<= 1) { a0 += __shfl_xor(a0, m); a1 += __shfl_xor(a1, m); }
    if (lane == 0) {
      float mn = a0 * (1.f / 256.f);
      float var = a1 * (1.f / 256.f) - mn * mn;
      mus[wave] = mn; rss[wave] = rsqrtf(var + EPSV);
    }
  }
  __syncthreads();
  for (int idx = t; idx < 2048; idx += 1024) {
    int s = idx >> 8, c = idx & 255;
    slnb[s * SP + c] = f2bf((sl[s][c] - mus[s]) * rss[s] * lsg[c] + lsb[c]);
  }
  __syncthreads();
  {
    f32x4 qa = 0.f;
    #pragma unroll
    for (int ks = 0; ks < 8; ks++) {
      int kof = (ks << 5) + kof0;
      bf16x8 a = *(const bf16x8*)&slnb[arow + kof];
      bf16x8 bb = *(const bf16x8*)(wq_b + (size_t)d * 256 + kof);
      qa = __builtin_amdgcn_mfma_f32_16x16x32_bf16(a, bb, qa, 0, 0, 0);
    }
    #pragma unroll
    for (int r = 0; r < 4; r++) {
      int s = (quad << 2) + r;
      if (s < 8) qb[(b << 11) + (s << 8) + d] = f2bf(qa[r]);
    }
  }
}

extern "C" void kernel_launch(void* const* d_in, const int* in_sizes, int n_in,
                              void* d_out, int out_size, void* d_ws, size_t ws_size,
                              hipStream_t stream) {
  const float* x        = (const float*)d_in[0];
  const float* slots_mu = (const float*)d_in[1];
  const float* ln_in_g  = (const float*)d_in[2];
  const float* ln_in_b  = (const float*)d_in[3];
  const float* wk       = (const float*)d_in[4];
  const float* wv       = (const float*)d_in[5];
  const float* ln_s_g   = (const float*)d_in[6];
  const float* ln_s_b   = (const float*)d_in[7];
  const float* wq       = (const float*)d_in[8];
  const float* wih      = (const float*)d_in[9];
  const float* whh      = (const float*)d_in[10];
  const float* bih      = (const float*)d_in[11];
  const float* bhh      = (const float*)d_in[12];
  const float* lmg      = (const float*)d_in[13];
  const float* lmb      = (const float*)d_in[14];
  const float* w1       = (const float*)d_in[15];
  const float* b1       = (const float*)d_in[16];
  const float* w2       = (const float*)d_in[17];
  const float* b2       = (const float*)d_in[18];
  float* out = (float*)d_out;
  float* out_attn = out + 131072;

  char* ws = (char*)d_ws;
  short* kbuf   = (short*)(ws);                  // 33,554,432 (xT then k in-place)
  short* vT     = (short*)(ws + 33554432);       // 33,554,432
  short* wkv_b  = (short*)(ws + 67108864);       //    262,144
  short* wq_b   = (short*)(ws + 67371008);       //    131,072
  short* wih_b  = (short*)(ws + 67502080);       //    393,216
  short* whh_b  = (short*)(ws + 67895296);       //    393,216
  short* w1_b   = (short*)(ws + 68288512);       //    131,072
  short* w2_b   = (short*)(ws + 68419584);       //    131,072
  float* slbuf  = (float*)(ws + 68550656);       //    524,288
  short* slbG   = (short*)(ws + 69074944);       //    262,144
  short* qb     = (short*)(ws + 69337088);       //    262,144
  short* parts  = (short*)(ws + 69599232);       //  4,194,304
  float* kvA    = (float*)(ws + 73793536);       //      2,048
  float* kvB    = (float*)(ws + 73795584);       //      2,048
  float* muB    = (float*)(ws + 73797632);       //    262,144
  float* rstdB  = (float*)(ws + 74059776);       //    262,144 -> 74,321,920

  wcvt<<<2304, 256, 0, stream>>>(wq, wih, whh, w1, w2,
                                 wq_b, wih_b, whh_b, w1_b, w2_b);
  wfold<<<512, 256, 0, stream>>>(wk, wv, ln_in_g, ln_in_b, wkv_b, kvA, kvB);
  xt_stats<<<512, 256, 0, stream>>>(x, kbuf, muB, rstdB);
  kv_gemm<<<512, 256, 0, stream>>>(kbuf, muB, rstdB, wkv_b, kvA, kvB, kbuf, vT);
  slot_init<<<64, 256, 0, stream>>>(slots_mu, ln_s_g, ln_s_b, wq_b, slbuf, slbG, qb);
  for (int it = 0; it < 3; it++) {
    attn_heavy<<<dim3(16, 64), 256, 0, stream>>>(kbuf, vT, qb, parts, out_attn,
                                                 (it == 2) ? 1 : 0);
    slot_reduce<<<64, 1024, 0, stream>>>(parts, slbuf, slbG, qb,
                                         wih_b, whh_b, bih, bhh, lmg, lmb,
                                         w1_b, b1, w2_b, b2, ln_s_g, ln_s_b, wq_b,
                                         out, (it == 2) ? 1 : 0);
  }
}

// Round 8
// 358.339 us; speedup vs baseline: 1.1016x; 1.0086x over previous
//
#include <hip/hip_runtime.h>

#define NPIX 1024
#define CIN  256
#define EPSV 1e-5f
#define SP 264
#define AP 72

typedef __attribute__((ext_vector_type(8))) short bf16x8;
typedef __attribute__((ext_vector_type(4))) float f32x4;

__device__ __forceinline__ short f2bf(float f) {
  unsigned u = __float_as_uint(f);
  unsigned r = (u + 0x7FFFu + ((u >> 16) & 1u)) >> 16;
  return (short)r;
}
__device__ __forceinline__ float b2f(short s) {
  return __uint_as_float(((unsigned)(unsigned short)s) << 16);
}

// ---------------- K0a: non-kv weights fp32 -> bf16 --------------------------
__global__ __launch_bounds__(256) void wcvt(
    const float* __restrict__ wq, const float* __restrict__ wih,
    const float* __restrict__ whh, const float* __restrict__ w1,
    const float* __restrict__ w2,
    short* __restrict__ wq_b, short* __restrict__ wih_b, short* __restrict__ whh_b,
    short* __restrict__ w1_b, short* __restrict__ w2_b) {
  int id = blockIdx.x * 256 + threadIdx.x;
  if      (id <  65536) wq_b [id         ] = f2bf(wq [id         ]);
  else if (id < 262144) wih_b[id -  65536] = f2bf(wih[id -  65536]);
  else if (id < 458752) whh_b[id - 262144] = f2bf(whh[id - 262144]);
  else if (id < 524288) w1_b [id - 458752] = f2bf(w1 [id - 458752]);
  else if (id < 589824) w2_b [id - 524288] = f2bf(w2 [id - 524288]);
}

// ---------------- K0b: wkv'=g*w (bf16) + wkT (transposed Wk') + A,B sums ----
__global__ __launch_bounds__(256) void wfold(
    const float* __restrict__ wk, const float* __restrict__ wv,
    const float* __restrict__ g, const float* __restrict__ bet,
    short* __restrict__ wkv_b, short* __restrict__ wkT_b,
    float* __restrict__ kvA, float* __restrict__ kvB) {
  __shared__ float ra[4], rb[4];
  int d = blockIdx.x;                 // 0..511
  int t = threadIdx.x;
  const float* wrow = (d < 256) ? (wk + (size_t)d * 256) : (wv + (size_t)(d - 256) * 256);
  float w = wrow[t], gg = g[t], bb = bet[t];
  float pa = gg * w, pb = bb * w;
  short hv = f2bf(pa);
  wkv_b[(size_t)d * 256 + t] = hv;
  if (d < 256) wkT_b[(size_t)t * 256 + d] = hv;   // Wk'^T[c][d]
  #pragma unroll
  for (int m = 1; m < 64; m <<= 1) { pa += __shfl_xor(pa, m); pb += __shfl_xor(pb, m); }
  int wave = t >> 6, lane = t & 63;
  if (lane == 0) { ra[wave] = pa; rb[wave] = pb; }
  __syncthreads();
  if (t == 0) {
    kvA[d] = ra[0] + ra[1] + ra[2] + ra[3];
    kvB[d] = rb[0] + rb[1] + rb[2] + rb[3];
  }
}

// ---------------- K1: x -> xT bf16 (transposed) + xO bf16 (cast) + LN stats -
__global__ __launch_bounds__(256) void xt_stats(
    const float* __restrict__ x, short* __restrict__ xT, short* __restrict__ xO,
    float* __restrict__ mu, float* __restrict__ rstd, short* __restrict__ muO) {
  __shared__ float ps[2][128], pq[2][128];
  int t = threadIdx.x;
  int pt = blockIdx.x & 7, b = blockIdx.x >> 3;
  int n0 = pt << 7;
  int q = t >> 2, j = t & 3;
  int pql = q & 31;
  int chal = t >> 7;
  int p0 = n0 + (pql << 2);
  const float* xb = x + (size_t)b * CIN * NPIX;
  short* xrow = xT + (size_t)((b << 10) + p0 + j) * 256;
  short* xob = xO + (size_t)b * 262144;
  float s = 0.f, sq = 0.f;
  #pragma unroll
  for (int i = 0; i < 16; i++) {
    bf16x8 o;
    #pragma unroll
    for (int sub = 0; sub < 2; sub++) {
      int c0 = (i << 4) + (chal << 3) + (sub << 2);
      float4 v = *(const float4*)(xb + (size_t)(c0 + j) * NPIX + p0);
      // xO: straight bf16 cast, original [c][p] layout
      short4 ov;
      ov.x = f2bf(v.x); ov.y = f2bf(v.y); ov.z = f2bf(v.z); ov.w = f2bf(v.w);
      *(short4*)(xob + (size_t)(c0 + j) * 1024 + p0) = ov;
      float v0 = v.x, v1 = v.y, v2 = v.z, v3 = v.w;
      float e0 = __shfl_xor((j & 1) ? v0 : v1, 1);
      float e1 = __shfl_xor((j & 1) ? v2 : v3, 1);
      if (j & 1) { v0 = e0; v2 = e1; } else { v1 = e0; v3 = e1; }
      float e2 = __shfl_xor((j & 2) ? v0 : v2, 2);
      float e3 = __shfl_xor((j & 2) ? v1 : v3, 2);
      if (j & 2) { v0 = e2; v1 = e3; } else { v2 = e2; v3 = e3; }
      s += v0 + v1 + v2 + v3;
      sq += v0 * v0 + v1 * v1 + v2 * v2 + v3 * v3;
      o[(sub << 2) + 0] = f2bf(v0);
      o[(sub << 2) + 1] = f2bf(v1);
      o[(sub << 2) + 2] = f2bf(v2);
      o[(sub << 2) + 3] = f2bf(v3);
    }
    *(bf16x8*)(xrow + (i << 4) + (chal << 3)) = o;
  }
  ps[chal][t & 127] = s;
  pq[chal][t & 127] = sq;
  __syncthreads();
  if (t < 128) {
    float ss = ps[0][t] + ps[1][t];
    float qq = pq[0][t] + pq[1][t];
    float m = ss * (1.f / 256.f);
    float var = qq * (1.f / 256.f) - m * m;
    int p = (b << 10) + n0 + t;
    mu[p] = m;
    rstd[p] = rsqrtf(var + EPSV);
    muO[p] = f2bf(m);
  }
}

// ---------------- K3: slot init — slots, LN_s, q0 -> qk0, Aq0/Bq0 -----------
__global__ __launch_bounds__(256) void slot_init(
    const float* __restrict__ slots_mu,
    const float* __restrict__ lsg, const float* __restrict__ lsb,
    const short* __restrict__ wq_b, const short* __restrict__ wkT_b,
    const float* __restrict__ kvA, const float* __restrict__ kvB,
    float* __restrict__ slbuf, short* __restrict__ slbG, short* __restrict__ qb,
    float* __restrict__ AqB, float* __restrict__ BqB) {
  __shared__ float sl[8][256];
  __shared__ float mus[8], rss[8];
  __shared__ __align__(16) short slnb[8 * SP], qlds[8 * SP];
  int b = blockIdx.x, t = threadIdx.x;
  int wave = t >> 6, lane = t & 63, quad = lane >> 4, lid = lane & 15;
  int arow = (lid & 7) * SP, kof0 = quad << 3;
  for (int idx = t; idx < 2048; idx += 256) {
    float v = slots_mu[idx];
    sl[idx >> 8][idx & 255] = v;
    slbuf[(b << 11) + idx] = v;
    slbG[(b << 11) + idx] = f2bf(v);
  }
  __syncthreads();
  {
    int s0 = (wave << 1) + (lane >> 5);
    int l32 = lane & 31;
    float a0 = 0.f, a1 = 0.f;
    #pragma unroll
    for (int j = 0; j < 8; j++) { float v = sl[s0][l32 + (j << 5)]; a0 += v; a1 += v * v; }
    #pragma unroll
    for (int m = 1; m < 32; m <<= 1) { a0 += __shfl_xor(a0, m); a1 += __shfl_xor(a1, m); }
    if (l32 == 0) {
      float mn = a0 * (1.f / 256.f);
      float var = a1 * (1.f / 256.f) - mn * mn;
      mus[s0] = mn; rss[s0] = rsqrtf(var + EPSV);
    }
  }
  __syncthreads();
  for (int idx = t; idx < 2048; idx += 256) {
    int s = idx >> 8, c = idx & 255;
    slnb[s * SP + c] = f2bf((sl[s][c] - mus[s]) * rss[s] * lsg[c] + lsb[c]);
  }
  __syncthreads();
  // q = LN_s(slots) @ wq^T -> qlds
  #pragma unroll
  for (int nt = 0; nt < 4; nt++) {
    int d = (wave << 6) + (nt << 4) + lid;
    f32x4 qa = 0.f;
    #pragma unroll
    for (int ks = 0; ks < 8; ks++) {
      bf16x8 a = *(const bf16x8*)&slnb[arow + (ks << 5) + kof0];
      bf16x8 bb = *(const bf16x8*)(wq_b + (size_t)d * 256 + (ks << 5) + kof0);
      qa = __builtin_amdgcn_mfma_f32_16x16x32_bf16(a, bb, qa, 0, 0, 0);
    }
    #pragma unroll
    for (int r = 0; r < 4; r++) {
      int s = (quad << 2) + r;
      if (s < 8) qlds[s * SP + d] = f2bf(qa[r]);
    }
  }
  __syncthreads();
  // qk = q @ Wk'^T^T (B = wkT rows, k=d contiguous) -> qb
  #pragma unroll
  for (int nt = 0; nt < 4; nt++) {
    int c = (wave << 6) + (nt << 4) + lid;
    f32x4 qa = 0.f;
    #pragma unroll
    for (int ks = 0; ks < 8; ks++) {
      bf16x8 a = *(const bf16x8*)&qlds[arow + (ks << 5) + kof0];
      bf16x8 bb = *(const bf16x8*)(wkT_b + (size_t)c * 256 + (ks << 5) + kof0);
      qa = __builtin_amdgcn_mfma_f32_16x16x32_bf16(a, bb, qa, 0, 0, 0);
    }
    #pragma unroll
    for (int r = 0; r < 4; r++) {
      int s = (quad << 2) + r;
      if (s < 8) qb[(b << 11) + (s << 8) + c] = f2bf(qa[r]);
    }
  }
  // Aq_s = q_s . kvA, Bq_s = q_s . kvB   (waves 0..3, two slots each)
  for (int s = wave; s < 8; s += 4) {
    float a0 = 0.f, a1 = 0.f;
    #pragma unroll
    for (int j = 0; j < 4; j++) {
      int dd = lane + (j << 6);
      float qv = b2f(qlds[s * SP + dd]);
      a0 += qv * kvA[dd]; a1 += qv * kvB[dd];
    }
    #pragma unroll
    for (int m = 1; m < 64; m <<= 1) { a0 += __shfl_xor(a0, m); a1 += __shfl_xor(a1, m); }
    if (lane == 0) { AqB[(b << 3) + s] = a0; BqB[(b << 3) + s] = a1; }
  }
}

// ---------------- K4: heavy — logits(+LN corrections) + softmax + y,cp ------
// grid (16 chunks, 64 b), block 256. chunk = 64 pixels.
__global__ __launch_bounds__(256) void attn_heavy(
    const short* __restrict__ xT, const short* __restrict__ xO,
    const short* __restrict__ qb,
    const float* __restrict__ muB, const float* __restrict__ rstdB,
    const short* __restrict__ muO,
    const float* __restrict__ AqB, const float* __restrict__ BqB,
    short* __restrict__ partials, float* __restrict__ cpbuf,
    float* __restrict__ out_attn, int write_attn) {
  __shared__ __align__(16) short attT[8 * AP];
  int chunk = blockIdx.x, b = blockIdx.y;
  int t = threadIdx.x, wave = t >> 6, lane = t & 63, quad = lane >> 4, lid = lane & 15;
  int kof0 = quad << 3;
  bf16x8 qf[8];
  const short* qpb = qb + ((size_t)b << 11) + (lid & 7) * 256 + kof0;
  #pragma unroll
  for (int ks = 0; ks < 8; ks++) qf[ks] = *(const bf16x8*)(qpb + (ks << 5));
  float Aq = AqB[(b << 3) + (lid & 7)];
  float Bq = BqB[(b << 3) + (lid & 7)];
  {
    int p0l = wave << 4;
    int pbase = (b << 10) + (chunk << 6) + p0l;
    const short* kb = xT + ((size_t)(pbase + lid)) * 256 + kof0;
    f32x4 la = 0.f;
    #pragma unroll
    for (int ks = 0; ks < 8; ks++) {
      bf16x8 a = *(const bf16x8*)(kb + (ks << 5));
      la = __builtin_amdgcn_mfma_f32_16x16x32_bf16(a, qf[ks], la, 0, 0, 0);
    }
    #pragma unroll
    for (int r = 0; r < 4; r++) {
      int p = pbase + (quad << 2) + r;
      float rs = rstdB[p], mm = muB[p];
      float lg = (rs * (la[r] - mm * Aq) + Bq) * 0.0625f;
      float mx = lg;
      #pragma unroll
      for (int m = 1; m < 16; m <<= 1) mx = fmaxf(mx, __shfl_xor(mx, m));
      float e = __expf(lg - mx);
      float sm = e;
      #pragma unroll
      for (int m = 1; m < 16; m <<= 1) sm += __shfl_xor(sm, m);
      float at = (e + e) / sm;
      if (lid < 8) {
        int pl = p0l + (quad << 2) + r;
        attT[lid * AP + pl] = f2bf(at * rs);   // fold rstd into attn weight
        if (write_attn) {
          int pg = (chunk << 6) + pl;
          out_attn[((size_t)b << 13) + (pg << 3) + lid] = at;
        }
      }
    }
  }
  __syncthreads();
  // y partials = attn'^T @ xO over this chunk's 64 pixels
  #pragma unroll
  for (int nt = 0; nt < 4; nt++) {
    int d0 = (wave << 6) + (nt << 4);
    f32x4 ua = 0.f;
    #pragma unroll
    for (int ks = 0; ks < 2; ks++) {
      bf16x8 a = *(const bf16x8*)&attT[(lid & 7) * AP + (ks << 5) + kof0];
      bf16x8 bb = *(const bf16x8*)(xO + (size_t)b * 262144 + (size_t)(d0 + lid) * 1024
                                   + (chunk << 6) + (ks << 5) + kof0);
      ua = __builtin_amdgcn_mfma_f32_16x16x32_bf16(a, bb, ua, 0, 0, 0);
    }
    #pragma unroll
    for (int r = 0; r < 4; r++) {
      int s = (quad << 2) + r;
      if (s < 8)
        partials[(((size_t)(b << 4) + chunk) << 11) + (s << 8) + d0 + lid] = f2bf(ua[r]);
    }
  }
  // cp partials = attn'^T @ mu  (B cols identical; one tile)
  if (wave == 0) {
    f32x4 ca = 0.f;
    #pragma unroll
    for (int ks = 0; ks < 2; ks++) {
      bf16x8 a = *(const bf16x8*)&attT[(lid & 7) * AP + (ks << 5) + kof0];
      bf16x8 bm = *(const bf16x8*)(muO + (b << 10) + (chunk << 6) + (ks << 5) + kof0);
      ca = __builtin_amdgcn_mfma_f32_16x16x32_bf16(a, bm, ca, 0, 0, 0);
    }
    if (lid == 0) {
      #pragma unroll
      for (int r = 0; r < 4; r++) {
        int s = (quad << 2) + r;
        if (s < 8) cpbuf[(((b << 4) + chunk) << 3) + s] = ca[r];
      }
    }
  }
}

// ---------------- K5: reduce y,cp + updates + GRU + MLP + (qk next) ---------
__global__ __launch_bounds__(1024) void slot_reduce(
    const short* __restrict__ partials, const float* __restrict__ cpbuf,
    float* __restrict__ slbuf, short* __restrict__ slbG, short* __restrict__ qb,
    const short* __restrict__ wkv_b, const short* __restrict__ wkT_b,
    const float* __restrict__ kvA, const float* __restrict__ kvB,
    const short* __restrict__ wih_b, const short* __restrict__ whh_b,
    const float* __restrict__ bih, const float* __restrict__ bhh,
    const float* __restrict__ lmg, const float* __restrict__ lmb,
    const short* __restrict__ w1_b, const float* __restrict__ b1,
    const short* __restrict__ w2_b, const float* __restrict__ b2,
    const float* __restrict__ lsg, const float* __restrict__ lsb,
    const short* __restrict__ wq_b,
    float* __restrict__ AqB, float* __restrict__ BqB,
    float* __restrict__ out, int last) {
  __shared__ float sl[8][256];
  __shared__ float mus[8], rss[8], cpl[8];
  __shared__ __align__(16) short ylds[8 * SP], updb[8 * SP], slb_l[8 * SP],
                                  lnmb[8 * SP], hmb[8 * SP], slnb[8 * SP], qlds[8 * SP];
  int b = blockIdx.x, t = threadIdx.x;
  int wave = t >> 6, lane = t & 63, quad = lane >> 4, lid = lane & 15;
  int arow = (lid & 7) * SP, kof0 = quad << 3;
  int d = (wave << 4) + lid;
  // ---- stage 0: vectorized y reduce + slot staging + cp reduce
  if (t < 256) {
    int s = t >> 5, d8 = (t & 31) << 3;
    float acc[8];
    #pragma unroll
    for (int i = 0; i < 8; i++) acc[i] = 0.f;
    #pragma unroll
    for (int c = 0; c < 16; c++) {
      bf16x8 v = *(const bf16x8*)(partials + ((((size_t)(b << 4) + c) << 11) + (s << 8) + d8));
      #pragma unroll
      for (int i = 0; i < 8; i++) acc[i] += b2f(v[i]);
    }
    bf16x8 o;
    #pragma unroll
    for (int i = 0; i < 8; i++) o[i] = f2bf(acc[i]);
    *(bf16x8*)&ylds[s * SP + d8] = o;
  } else if (t < 512) {
    int tt = t - 256;
    int s = tt >> 5, d8 = (tt & 31) << 3;
    bf16x8 v = *(const bf16x8*)(slbG + ((b << 11) + (s << 8) + d8));
    *(bf16x8*)&slb_l[s * SP + d8] = v;
  } else if (t < 768) {
    int tt = t - 512;
    int s = tt >> 5, d8 = (tt & 31) << 3;
    float4 v0 = *(const float4*)(slbuf + ((b << 11) + (s << 8) + d8));
    float4 v1 = *(const float4*)(slbuf + ((b << 11) + (s << 8) + d8 + 4));
    *(float4*)&sl[s][d8] = v0;
    *(float4*)&sl[s][d8 + 4] = v1;
  } else if (t < 776) {
    int s = t - 768;
    float c = 0.f;
    #pragma unroll
    for (int cc = 0; cc < 16; cc++) c += cpbuf[(((b << 4) + cc) << 3) + s];
    cpl[s] = c;
  }
  __syncthreads();
  // ---- stage 0.5: updates = y @ Wv'^T - cp*Av + Bv
  {
    f32x4 oa = 0.f;
    #pragma unroll
    for (int ks = 0; ks < 8; ks++) {
      int kof = (ks << 5) + kof0;
      bf16x8 a = *(const bf16x8*)&ylds[arow + kof];
      bf16x8 bb = *(const bf16x8*)(wkv_b + (size_t)(256 + d) * 256 + kof);
      oa = __builtin_amdgcn_mfma_f32_16x16x32_bf16(a, bb, oa, 0, 0, 0);
    }
    float Av = kvA[256 + d], Bv = kvB[256 + d];
    #pragma unroll
    for (int r = 0; r < 4; r++) {
      int s = (quad << 2) + r;
      if (s < 8) updb[s * SP + d] = f2bf(oa[r] - cpl[s] * Av + Bv);
    }
  }
  __syncthreads();
  // ---- stage 1: GRU — all 6 gate GEMMs for this wave's 16 columns
  {
    f32x4 gi0 = 0.f, gi1 = 0.f, gi2 = 0.f, gh0 = 0.f, gh1 = 0.f, gh2 = 0.f;
    #pragma unroll
    for (int ks = 0; ks < 8; ks++) {
      int kof = (ks << 5) + kof0;
      bf16x8 au = *(const bf16x8*)&updb [arow + kof];
      bf16x8 ah = *(const bf16x8*)&slb_l[arow + kof];
      bf16x8 w0 = *(const bf16x8*)(wih_b + (size_t)(0 * 256 + d) * 256 + kof);
      bf16x8 w1r = *(const bf16x8*)(wih_b + (size_t)(1 * 256 + d) * 256 + kof);
      bf16x8 w2r = *(const bf16x8*)(wih_b + (size_t)(2 * 256 + d) * 256 + kof);
      bf16x8 u0 = *(const bf16x8*)(whh_b + (size_t)(0 * 256 + d) * 256 + kof);
      bf16x8 u1 = *(const bf16x8*)(whh_b + (size_t)(1 * 256 + d) * 256 + kof);
      bf16x8 u2 = *(const bf16x8*)(whh_b + (size_t)(2 * 256 + d) * 256 + kof);
      gi0 = __builtin_amdgcn_mfma_f32_16x16x32_bf16(au, w0, gi0, 0, 0, 0);
      gi1 = __builtin_amdgcn_mfma_f32_16x16x32_bf16(au, w1r, gi1, 0, 0, 0);
      gi2 = __builtin_amdgcn_mfma_f32_16x16x32_bf16(au, w2r, gi2, 0, 0, 0);
      gh0 = __builtin_amdgcn_mfma_f32_16x16x32_bf16(ah, u0, gh0, 0, 0, 0);
      gh1 = __builtin_amdgcn_mfma_f32_16x16x32_bf16(ah, u1, gh1, 0, 0, 0);
      gh2 = __builtin_amdgcn_mfma_f32_16x16x32_bf16(ah, u2, gh2, 0, 0, 0);
    }
    float bi0 = bih[d], bi1 = bih[256 + d], bi2 = bih[512 + d];
    float bh0 = bhh[d], bh1 = bhh[256 + d], bh2 = bhh[512 + d];
    #pragma unroll
    for (int r = 0; r < 4; r++) {
      int s = (quad << 2) + r;
      if (s < 8) {
        float rg = 1.f / (1.f + __expf(-(gi0[r] + bi0 + gh0[r] + bh0)));
        float zg = 1.f / (1.f + __expf(-(gi1[r] + bi1 + gh1[r] + bh1)));
        float ng = tanhf(gi2[r] + bi2 + rg * (gh2[r] + bh2));
        sl[s][d] = (1.f - zg) * ng + zg * sl[s][d];
      }
    }
  }
  __syncthreads();
  // ---- stage 2: LN_m
  if (wave < 8) {
    float a0 = 0.f, a1 = 0.f;
    #pragma unroll
    for (int j = 0; j < 4; j++) { float v = sl[wave][lane + (j << 6)]; a0 += v; a1 += v * v; }
    #pragma unroll
    for (int m = 1; m < 64; m <<= 1) { a0 += __shfl_xor(a0, m); a1 += __shfl_xor(a1, m); }
    if (lane == 0) {
      float mn = a0 * (1.f / 256.f);
      float var = a1 * (1.f / 256.f) - mn * mn;
      mus[wave] = mn; rss[wave] = rsqrtf(var + EPSV);
    }
  }
  __syncthreads();
  for (int idx = t; idx < 2048; idx += 1024) {
    int s = idx >> 8, c = idx & 255;
    lnmb[s * SP + c] = f2bf((sl[s][c] - mus[s]) * rss[s] * lmg[c] + lmb[c]);
  }
  __syncthreads();
  // ---- stage 3: MLP layer 1
  {
    f32x4 ha = 0.f;
    #pragma unroll
    for (int ks = 0; ks < 8; ks++) {
      int kof = (ks << 5) + kof0;
      bf16x8 a = *(const bf16x8*)&lnmb[arow + kof];
      bf16x8 bb = *(const bf16x8*)(w1_b + (size_t)d * 256 + kof);
      ha = __builtin_amdgcn_mfma_f32_16x16x32_bf16(a, bb, ha, 0, 0, 0);
    }
    float bb1 = b1[d];
    #pragma unroll
    for (int r = 0; r < 4; r++) {
      int s = (quad << 2) + r;
      if (s < 8) hmb[s * SP + d] = f2bf(fmaxf(ha[r] + bb1, 0.f));
    }
  }
  __syncthreads();
  // ---- stage 4: MLP layer 2 + residual
  {
    f32x4 oa = 0.f;
    #pragma unroll
    for (int ks = 0; ks < 8; ks++) {
      int kof = (ks << 5) + kof0;
      bf16x8 a = *(const bf16x8*)&hmb[arow + kof];
      bf16x8 bb = *(const bf16x8*)(w2_b + (size_t)d * 256 + kof);
      oa = __builtin_amdgcn_mfma_f32_16x16x32_bf16(a, bb, oa, 0, 0, 0);
    }
    float bb2 = b2[d];
    #pragma unroll
    for (int r = 0; r < 4; r++) {
      int s = (quad << 2) + r;
      if (s < 8) sl[s][d] = sl[s][d] + oa[r] + bb2;
    }
  }
  __syncthreads();
  if (last) {
    for (int idx = t; idx < 2048; idx += 1024)
      out[(b << 11) + idx] = sl[idx >> 8][idx & 255];
    return;
  }
  // ---- stage 5: persist slots; LN_s; q -> qlds
  for (int idx = t; idx < 2048; idx += 1024) {
    float v = sl[idx >> 8][idx & 255];
    slbuf[(b << 11) + idx] = v;
    slbG[(b << 11) + idx] = f2bf(v);
  }
  if (wave < 8) {
    float a0 = 0.f, a1 = 0.f;
    #pragma unroll
    for (int j = 0; j < 4; j++) { float v = sl[wave][lane + (j << 6)]; a0 += v; a1 += v * v; }
    #pragma unroll
    for (int m = 1; m < 64; m <<= 1) { a0 += __shfl_xor(a0, m); a1 += __shfl_xor(a1, m); }
    if (lane == 0) {
      float mn = a0 * (1.f / 256.f);
      float var = a1 * (1.f / 256.f) - mn * mn;
      mus[wave] = mn; rss[wave] = rsqrtf(var + EPSV);
    }
  }
  __syncthreads();
  for (int idx = t; idx < 2048; idx += 1024) {
    int s = idx >> 8, c = idx & 255;
    slnb[s * SP + c] = f2bf((sl[s][c] - mus[s]) * rss[s] * lsg[c] + lsb[c]);
  }
  __syncthreads();
  {
    f32x4 qa = 0.f;
    #pragma unroll
    for (int ks = 0; ks < 8; ks++) {
      int kof = (ks << 5) + kof0;
      bf16x8 a = *(const bf16x8*)&slnb[arow + kof];
      bf16x8 bb = *(const bf16x8*)(wq_b + (size_t)d * 256 + kof);
      qa = __builtin_amdgcn_mfma_f32_16x16x32_bf16(a, bb, qa, 0, 0, 0);
    }
    #pragma unroll
    for (int r = 0; r < 4; r++) {
      int s = (quad << 2) + r;
      if (s < 8) qlds[s * SP + d] = f2bf(qa[r]);
    }
  }
  __syncthreads();
  // ---- stage 6: qk = q @ wkT rows; Aq/Bq dots
  {
    f32x4 qa = 0.f;
    #pragma unroll
    for (int ks = 0; ks < 8; ks++) {
      int kof = (ks << 5) + kof0;
      bf16x8 a = *(const bf16x8*)&qlds[arow + kof];
      bf16x8 bb = *(const bf16x8*)(wkT_b + (size_t)d * 256 + kof);
      qa = __builtin_amdgcn_mfma_f32_16x16x32_bf16(a, bb, qa, 0, 0, 0);
    }
    #pragma unroll
    for (int r = 0; r < 4; r++) {
      int s = (quad << 2) + r;
      if (s < 8) qb[(b << 11) + (s << 8) + d] = f2bf(qa[r]);
    }
  }
  if (wave < 8) {
    int s = wave;
    float a0 = 0.f, a1 = 0.f;
    #pragma unroll
    for (int j = 0; j < 4; j++) {
      int dd = lane + (j << 6);
      float qv = b2f(qlds[s * SP + dd]);
      a0 += qv * kvA[dd]; a1 += qv * kvB[dd];
    }
    #pragma unroll
    for (int m = 1; m < 64; m <<= 1) { a0 += __shfl_xor(a0, m); a1 += __shfl_xor(a1, m); }
    if (lane == 0) { AqB[(b << 3) + s] = a0; BqB[(b << 3) + s] = a1; }
  }
}

extern "C" void kernel_launch(void* const* d_in, const int* in_sizes, int n_in,
                              void* d_out, int out_size, void* d_ws, size_t ws_size,
                              hipStream_t stream) {
  const float* x        = (const float*)d_in[0];
  const float* slots_mu = (const float*)d_in[1];
  const float* ln_in_g  = (const float*)d_in[2];
  const float* ln_in_b  = (const float*)d_in[3];
  const float* wk       = (const float*)d_in[4];
  const float* wv       = (const float*)d_in[5];
  const float* ln_s_g   = (const float*)d_in[6];
  const float* ln_s_b   = (const float*)d_in[7];
  const float* wq       = (const float*)d_in[8];
  const float* wih      = (const float*)d_in[9];
  const float* whh      = (const float*)d_in[10];
  const float* bih      = (const float*)d_in[11];
  const float* bhh      = (const float*)d_in[12];
  const float* lmg      = (const float*)d_in[13];
  const float* lmb      = (const float*)d_in[14];
  const float* w1       = (const float*)d_in[15];
  const float* b1       = (const float*)d_in[16];
  const float* w2       = (const float*)d_in[17];
  const float* b2       = (const float*)d_in[18];
  float* out = (float*)d_out;
  float* out_attn = out + 131072;

  char* ws = (char*)d_ws;
  short* xT     = (short*)(ws);                  // 33,554,432
  short* xO     = (short*)(ws + 33554432);       // 33,554,432
  short* wkv_b  = (short*)(ws + 67108864);       //    262,144
  short* wq_b   = (short*)(ws + 67371008);       //    131,072
  short* wih_b  = (short*)(ws + 67502080);       //    393,216
  short* whh_b  = (short*)(ws + 67895296);       //    393,216
  short* w1_b   = (short*)(ws + 68288512);       //    131,072
  short* w2_b   = (short*)(ws + 68419584);       //    131,072
  float* slbuf  = (float*)(ws + 68550656);       //    524,288
  short* slbG   = (short*)(ws + 69074944);       //    262,144
  short* qb     = (short*)(ws + 69337088);       //    262,144
  short* parts  = (short*)(ws + 69599232);       //  4,194,304
  float* kvA    = (float*)(ws + 73793536);       //      2,048
  float* kvB    = (float*)(ws + 73795584);       //      2,048
  float* muB    = (float*)(ws + 73797632);       //    262,144
  float* rstdB  = (float*)(ws + 74059776);       //    262,144
  short* wkT_b  = (short*)(ws + 74321920);       //    131,072
  short* muO    = (short*)(ws + 74452992);       //    131,072
  float* cpbuf  = (float*)(ws + 74584064);       //     32,768
  float* AqB    = (float*)(ws + 74616832);       //      2,048
  float* BqB    = (float*)(ws + 74618880);       //      2,048 -> 74,620,928

  wcvt<<<2304, 256, 0, stream>>>(wq, wih, whh, w1, w2,
                                 wq_b, wih_b, whh_b, w1_b, w2_b);
  wfold<<<512, 256, 0, stream>>>(wk, wv, ln_in_g, ln_in_b, wkv_b, wkT_b, kvA, kvB);
  xt_stats<<<512, 256, 0, stream>>>(x, xT, xO, muB, rstdB, muO);
  slot_init<<<64, 256, 0, stream>>>(slots_mu, ln_s_g, ln_s_b, wq_b, wkT_b,
                                    kvA, kvB, slbuf, slbG, qb, AqB, BqB);
  for (int it = 0; it < 3; it++) {
    attn_heavy<<<dim3(16, 64), 256, 0, stream>>>(xT, xO, qb, muB, rstdB, muO,
                                                 AqB, BqB, parts, cpbuf, out_attn,
                                                 (it == 2) ? 1 : 0);
    slot_reduce<<<64, 1024, 0, stream>>>(parts, cpbuf, slbuf, slbG, qb,
                                         wkv_b, wkT_b, kvA, kvB,
                                         wih_b, whh_b, bih, bhh, lmg, lmb,
                                         w1_b, b1, w2_b, b2, ln_s_g, ln_s_b, wq_b,
                                         AqB, BqB, out, (it == 2) ? 1 : 0);
  }
}

// Round 9
// 353.852 us; speedup vs baseline: 1.1156x; 1.0127x over previous
//
#include <hip/hip_runtime.h>

#define NPIX 1024
#define CIN  256
#define EPSV 1e-5f
#define SP 264
#define AP 72

typedef __attribute__((ext_vector_type(8))) short bf16x8;
typedef __attribute__((ext_vector_type(4))) float f32x4;

__device__ __forceinline__ short f2bf(float f) {
  unsigned u = __float_as_uint(f);
  unsigned r = (u + 0x7FFFu + ((u >> 16) & 1u)) >> 16;
  return (short)r;
}
__device__ __forceinline__ float b2f(short s) {
  return __uint_as_float(((unsigned)(unsigned short)s) << 16);
}

// ---------------- K0a: non-kv weights fp32 -> bf16 --------------------------
__global__ __launch_bounds__(256) void wcvt(
    const float* __restrict__ wq, const float* __restrict__ wih,
    const float* __restrict__ whh, const float* __restrict__ w1,
    const float* __restrict__ w2,
    short* __restrict__ wq_b, short* __restrict__ wih_b, short* __restrict__ whh_b,
    short* __restrict__ w1_b, short* __restrict__ w2_b) {
  int id = blockIdx.x * 256 + threadIdx.x;
  if      (id <  65536) wq_b [id         ] = f2bf(wq [id         ]);
  else if (id < 262144) wih_b[id -  65536] = f2bf(wih[id -  65536]);
  else if (id < 458752) whh_b[id - 262144] = f2bf(whh[id - 262144]);
  else if (id < 524288) w1_b [id - 458752] = f2bf(w1 [id - 458752]);
  else if (id < 589824) w2_b [id - 524288] = f2bf(w2 [id - 524288]);
}

// ---------------- K0b: wkv'=g*w (bf16) + wkT (transposed Wk') + A,B sums ----
__global__ __launch_bounds__(256) void wfold(
    const float* __restrict__ wk, const float* __restrict__ wv,
    const float* __restrict__ g, const float* __restrict__ bet,
    short* __restrict__ wkv_b, short* __restrict__ wkT_b,
    float* __restrict__ kvA, float* __restrict__ kvB) {
  __shared__ float ra[4], rb[4];
  int d = blockIdx.x;                 // 0..511
  int t = threadIdx.x;
  const float* wrow = (d < 256) ? (wk + (size_t)d * 256) : (wv + (size_t)(d - 256) * 256);
  float w = wrow[t], gg = g[t], bb = bet[t];
  float pa = gg * w, pb = bb * w;
  short hv = f2bf(pa);
  wkv_b[(size_t)d * 256 + t] = hv;
  if (d < 256) wkT_b[(size_t)t * 256 + d] = hv;   // Wk'^T[c][d]
  #pragma unroll
  for (int m = 1; m < 64; m <<= 1) { pa += __shfl_xor(pa, m); pb += __shfl_xor(pb, m); }
  int wave = t >> 6, lane = t & 63;
  if (lane == 0) { ra[wave] = pa; rb[wave] = pb; }
  __syncthreads();
  if (t == 0) {
    kvA[d] = ra[0] + ra[1] + ra[2] + ra[3];
    kvB[d] = rb[0] + rb[1] + rb[2] + rb[3];
  }
}

// ---------------- K1: x -> xT bf16 (transposed) + LN stats ------------------
// grid (32 pixel-tiles, 64 b), block 256. Tile = 32 pixels x 256 c.
// thread: j=t&3 (pixel-in-quad), pql=(t>>2)&7 (pixel-quad), cg=t>>5 (c-group).
// 8 float4 loads/thread; quad shfl 4x4 transpose; 4x 16B xT stores/thread.
__global__ __launch_bounds__(256) void xt_stats(
    const float* __restrict__ x, short* __restrict__ xT,
    float* __restrict__ mu, float* __restrict__ rstd, short* __restrict__ muO) {
  __shared__ float ps[32][9], pq[32][9];
  int t = threadIdx.x;
  int pt = blockIdx.x, b = blockIdx.y;
  int j = t & 3, pql = (t >> 2) & 7, cg = t >> 5;
  int P0 = (pt << 5) + (pql << 2);            // global pixel base (quad)
  const float* xb = x + (size_t)b * CIN * NPIX;
  short* xrow = xT + (size_t)((b << 10) + P0 + j) * 256 + (cg << 5);
  float s = 0.f, sq = 0.f;
  bf16x8 o;
  #pragma unroll
  for (int i = 0; i < 8; i++) {
    int c0 = (cg << 5) + (i << 2);
    float4 v = *(const float4*)(xb + (size_t)(c0 + j) * NPIX + P0);
    float v0 = v.x, v1 = v.y, v2 = v.z, v3 = v.w;
    // 4x4 quad transpose (verified R6)
    float e0 = __shfl_xor((j & 1) ? v0 : v1, 1);
    float e1 = __shfl_xor((j & 1) ? v2 : v3, 1);
    if (j & 1) { v0 = e0; v2 = e1; } else { v1 = e0; v3 = e1; }
    float e2 = __shfl_xor((j & 2) ? v0 : v2, 2);
    float e3 = __shfl_xor((j & 2) ? v1 : v3, 2);
    if (j & 2) { v0 = e2; v1 = e3; } else { v2 = e2; v3 = e3; }
    s += v0 + v1 + v2 + v3;
    sq += v0 * v0 + v1 * v1 + v2 * v2 + v3 * v3;
    int h = (i & 1) << 2;
    o[h + 0] = f2bf(v0); o[h + 1] = f2bf(v1); o[h + 2] = f2bf(v2); o[h + 3] = f2bf(v3);
    if (i & 1) *(bf16x8*)(xrow + ((i - 1) << 2)) = o;
  }
  ps[(pql << 2) + j][cg] = s;
  pq[(pql << 2) + j][cg] = sq;
  __syncthreads();
  if (t < 32) {
    float ss = 0.f, qq = 0.f;
    #pragma unroll
    for (int g2 = 0; g2 < 8; g2++) { ss += ps[t][g2]; qq += pq[t][g2]; }
    float m = ss * (1.f / 256.f);
    float var = qq * (1.f / 256.f) - m * m;
    int p = (b << 10) + (pt << 5) + t;
    mu[p] = m;
    rstd[p] = rsqrtf(var + EPSV);
    muO[p] = f2bf(m);
  }
}

// ---------------- K3: slot init — slots, LN_s, q0 -> qk0, Aq0/Bq0 -----------
__global__ __launch_bounds__(256) void slot_init(
    const float* __restrict__ slots_mu,
    const float* __restrict__ lsg, const float* __restrict__ lsb,
    const short* __restrict__ wq_b, const short* __restrict__ wkT_b,
    const float* __restrict__ kvA, const float* __restrict__ kvB,
    float* __restrict__ slbuf, short* __restrict__ slbG, short* __restrict__ qb,
    float* __restrict__ AqB, float* __restrict__ BqB) {
  __shared__ float sl[8][256];
  __shared__ float mus[8], rss[8];
  __shared__ __align__(16) short slnb[8 * SP], qlds[8 * SP];
  int b = blockIdx.x, t = threadIdx.x;
  int wave = t >> 6, lane = t & 63, quad = lane >> 4, lid = lane & 15;
  int arow = (lid & 7) * SP, kof0 = quad << 3;
  for (int idx = t; idx < 2048; idx += 256) {
    float v = slots_mu[idx];
    sl[idx >> 8][idx & 255] = v;
    slbuf[(b << 11) + idx] = v;
    slbG[(b << 11) + idx] = f2bf(v);
  }
  __syncthreads();
  {
    int s0 = (wave << 1) + (lane >> 5);
    int l32 = lane & 31;
    float a0 = 0.f, a1 = 0.f;
    #pragma unroll
    for (int j = 0; j < 8; j++) { float v = sl[s0][l32 + (j << 5)]; a0 += v; a1 += v * v; }
    #pragma unroll
    for (int m = 1; m < 32; m <<= 1) { a0 += __shfl_xor(a0, m); a1 += __shfl_xor(a1, m); }
    if (l32 == 0) {
      float mn = a0 * (1.f / 256.f);
      float var = a1 * (1.f / 256.f) - mn * mn;
      mus[s0] = mn; rss[s0] = rsqrtf(var + EPSV);
    }
  }
  __syncthreads();
  for (int idx = t; idx < 2048; idx += 256) {
    int s = idx >> 8, c = idx & 255;
    slnb[s * SP + c] = f2bf((sl[s][c] - mus[s]) * rss[s] * lsg[c] + lsb[c]);
  }
  __syncthreads();
  #pragma unroll
  for (int nt = 0; nt < 4; nt++) {
    int d = (wave << 6) + (nt << 4) + lid;
    f32x4 qa = 0.f;
    #pragma unroll
    for (int ks = 0; ks < 8; ks++) {
      bf16x8 a = *(const bf16x8*)&slnb[arow + (ks << 5) + kof0];
      bf16x8 bb = *(const bf16x8*)(wq_b + (size_t)d * 256 + (ks << 5) + kof0);
      qa = __builtin_amdgcn_mfma_f32_16x16x32_bf16(a, bb, qa, 0, 0, 0);
    }
    #pragma unroll
    for (int r = 0; r < 4; r++) {
      int s = (quad << 2) + r;
      if (s < 8) qlds[s * SP + d] = f2bf(qa[r]);
    }
  }
  __syncthreads();
  #pragma unroll
  for (int nt = 0; nt < 4; nt++) {
    int c = (wave << 6) + (nt << 4) + lid;
    f32x4 qa = 0.f;
    #pragma unroll
    for (int ks = 0; ks < 8; ks++) {
      bf16x8 a = *(const bf16x8*)&qlds[arow + (ks << 5) + kof0];
      bf16x8 bb = *(const bf16x8*)(wkT_b + (size_t)c * 256 + (ks << 5) + kof0);
      qa = __builtin_amdgcn_mfma_f32_16x16x32_bf16(a, bb, qa, 0, 0, 0);
    }
    #pragma unroll
    for (int r = 0; r < 4; r++) {
      int s = (quad << 2) + r;
      if (s < 8) qb[(b << 11) + (s << 8) + c] = f2bf(qa[r]);
    }
  }
  for (int s = wave; s < 8; s += 4) {
    float a0 = 0.f, a1 = 0.f;
    #pragma unroll
    for (int j = 0; j < 4; j++) {
      int dd = lane + (j << 6);
      float qv = b2f(qlds[s * SP + dd]);
      a0 += qv * kvA[dd]; a1 += qv * kvB[dd];
    }
    #pragma unroll
    for (int m = 1; m < 64; m <<= 1) { a0 += __shfl_xor(a0, m); a1 += __shfl_xor(a1, m); }
    if (lane == 0) { AqB[(b << 3) + s] = a0; BqB[(b << 3) + s] = a1; }
  }
}

// ---------------- K4: heavy — logits(+LN corr) + softmax + y,cp -------------
// grid (16 chunks, 64 b), block 256. y-GEMM reads fp32 x directly (L3-hot).
__global__ __launch_bounds__(256) void attn_heavy(
    const short* __restrict__ xT, const float* __restrict__ x,
    const short* __restrict__ qb,
    const float* __restrict__ muB, const float* __restrict__ rstdB,
    const short* __restrict__ muO,
    const float* __restrict__ AqB, const float* __restrict__ BqB,
    short* __restrict__ partials, float* __restrict__ cpbuf,
    float* __restrict__ out_attn, int write_attn) {
  __shared__ __align__(16) short attT[8 * AP];
  int chunk = blockIdx.x, b = blockIdx.y;
  int t = threadIdx.x, wave = t >> 6, lane = t & 63, quad = lane >> 4, lid = lane & 15;
  int kof0 = quad << 3;
  bf16x8 qf[8];
  const short* qpb = qb + ((size_t)b << 11) + (lid & 7) * 256 + kof0;
  #pragma unroll
  for (int ks = 0; ks < 8; ks++) qf[ks] = *(const bf16x8*)(qpb + (ks << 5));
  float Aq = AqB[(b << 3) + (lid & 7)];
  float Bq = BqB[(b << 3) + (lid & 7)];
  {
    int p0l = wave << 4;
    int pbase = (b << 10) + (chunk << 6) + p0l;
    const short* kb = xT + ((size_t)(pbase + lid)) * 256 + kof0;
    f32x4 la = 0.f;
    #pragma unroll
    for (int ks = 0; ks < 8; ks++) {
      bf16x8 a = *(const bf16x8*)(kb + (ks << 5));
      la = __builtin_amdgcn_mfma_f32_16x16x32_bf16(a, qf[ks], la, 0, 0, 0);
    }
    #pragma unroll
    for (int r = 0; r < 4; r++) {
      int p = pbase + (quad << 2) + r;
      float rs = rstdB[p], mm = muB[p];
      float lg = (rs * (la[r] - mm * Aq) + Bq) * 0.0625f;
      float mx = lg;
      #pragma unroll
      for (int m = 1; m < 16; m <<= 1) mx = fmaxf(mx, __shfl_xor(mx, m));
      float e = __expf(lg - mx);
      float sm = e;
      #pragma unroll
      for (int m = 1; m < 16; m <<= 1) sm += __shfl_xor(sm, m);
      float at = (e + e) / sm;
      if (lid < 8) {
        int pl = p0l + (quad << 2) + r;
        attT[lid * AP + pl] = f2bf(at * rs);   // fold rstd into attn weight
        if (write_attn) {
          int pg = (chunk << 6) + pl;
          out_attn[((size_t)b << 13) + (pg << 3) + lid] = at;
        }
      }
    }
  }
  __syncthreads();
  // y partials = attn'^T @ bf16(x) over this chunk's 64 pixels
  #pragma unroll
  for (int nt = 0; nt < 4; nt++) {
    int d0 = (wave << 6) + (nt << 4);
    f32x4 ua = 0.f;
    #pragma unroll
    for (int ks = 0; ks < 2; ks++) {
      bf16x8 a = *(const bf16x8*)&attT[(lid & 7) * AP + (ks << 5) + kof0];
      const float* xf = x + (size_t)b * 262144 + (size_t)(d0 + lid) * 1024
                        + (chunk << 6) + (ks << 5) + kof0;
      float4 va = *(const float4*)xf;
      float4 vb2 = *(const float4*)(xf + 4);
      bf16x8 bb;
      bb[0] = f2bf(va.x);  bb[1] = f2bf(va.y);  bb[2] = f2bf(va.z);  bb[3] = f2bf(va.w);
      bb[4] = f2bf(vb2.x); bb[5] = f2bf(vb2.y); bb[6] = f2bf(vb2.z); bb[7] = f2bf(vb2.w);
      ua = __builtin_amdgcn_mfma_f32_16x16x32_bf16(a, bb, ua, 0, 0, 0);
    }
    #pragma unroll
    for (int r = 0; r < 4; r++) {
      int s = (quad << 2) + r;
      if (s < 8)
        partials[(((size_t)(b << 4) + chunk) << 11) + (s << 8) + d0 + lid] = f2bf(ua[r]);
    }
  }
  // cp partials = attn'^T @ mu
  if (wave == 0) {
    f32x4 ca = 0.f;
    #pragma unroll
    for (int ks = 0; ks < 2; ks++) {
      bf16x8 a = *(const bf16x8*)&attT[(lid & 7) * AP + (ks << 5) + kof0];
      bf16x8 bm = *(const bf16x8*)(muO + (b << 10) + (chunk << 6) + (ks << 5) + kof0);
      ca = __builtin_amdgcn_mfma_f32_16x16x32_bf16(a, bm, ca, 0, 0, 0);
    }
    if (lid == 0) {
      #pragma unroll
      for (int r = 0; r < 4; r++) {
        int s = (quad << 2) + r;
        if (s < 8) cpbuf[(((b << 4) + chunk) << 3) + s] = ca[r];
      }
    }
  }
}

// ---------------- K5: reduce y,cp + updates + GRU + MLP + (qk next) ---------
__global__ __launch_bounds__(1024) void slot_reduce(
    const short* __restrict__ partials, const float* __restrict__ cpbuf,
    float* __restrict__ slbuf, short* __restrict__ slbG, short* __restrict__ qb,
    const short* __restrict__ wkv_b, const short* __restrict__ wkT_b,
    const float* __restrict__ kvA, const float* __restrict__ kvB,
    const short* __restrict__ wih_b, const short* __restrict__ whh_b,
    const float* __restrict__ bih, const float* __restrict__ bhh,
    const float* __restrict__ lmg, const float* __restrict__ lmb,
    const short* __restrict__ w1_b, const float* __restrict__ b1,
    const short* __restrict__ w2_b, const float* __restrict__ b2,
    const float* __restrict__ lsg, const float* __restrict__ lsb,
    const short* __restrict__ wq_b,
    float* __restrict__ AqB, float* __restrict__ BqB,
    float* __restrict__ out, int last) {
  __shared__ float sl[8][256];
  __shared__ float mus[8], rss[8], cpl[8];
  __shared__ __align__(16) short ylds[8 * SP], updb[8 * SP], slb_l[8 * SP],
                                  lnmb[8 * SP], hmb[8 * SP], slnb[8 * SP], qlds[8 * SP];
  int b = blockIdx.x, t = threadIdx.x;
  int wave = t >> 6, lane = t & 63, quad = lane >> 4, lid = lane & 15;
  int arow = (lid & 7) * SP, kof0 = quad << 3;
  int d = (wave << 4) + lid;
  if (t < 256) {
    int s = t >> 5, d8 = (t & 31) << 3;
    float acc[8];
    #pragma unroll
    for (int i = 0; i < 8; i++) acc[i] = 0.f;
    #pragma unroll
    for (int c = 0; c < 16; c++) {
      bf16x8 v = *(const bf16x8*)(partials + ((((size_t)(b << 4) + c) << 11) + (s << 8) + d8));
      #pragma unroll
      for (int i = 0; i < 8; i++) acc[i] += b2f(v[i]);
    }
    bf16x8 o;
    #pragma unroll
    for (int i = 0; i < 8; i++) o[i] = f2bf(acc[i]);
    *(bf16x8*)&ylds[s * SP + d8] = o;
  } else if (t < 512) {
    int tt = t - 256;
    int s = tt >> 5, d8 = (tt & 31) << 3;
    bf16x8 v = *(const bf16x8*)(slbG + ((b << 11) + (s << 8) + d8));
    *(bf16x8*)&slb_l[s * SP + d8] = v;
  } else if (t < 768) {
    int tt = t - 512;
    int s = tt >> 5, d8 = (tt & 31) << 3;
    float4 v0 = *(const float4*)(slbuf + ((b << 11) + (s << 8) + d8));
    float4 v1 = *(const float4*)(slbuf + ((b << 11) + (s << 8) + d8 + 4));
    *(float4*)&sl[s][d8] = v0;
    *(float4*)&sl[s][d8 + 4] = v1;
  } else if (t < 776) {
    int s = t - 768;
    float c = 0.f;
    #pragma unroll
    for (int cc = 0; cc < 16; cc++) c += cpbuf[(((b << 4) + cc) << 3) + s];
    cpl[s] = c;
  }
  __syncthreads();
  {
    f32x4 oa = 0.f;
    #pragma unroll
    for (int ks = 0; ks < 8; ks++) {
      int kof = (ks << 5) + kof0;
      bf16x8 a = *(const bf16x8*)&ylds[arow + kof];
      bf16x8 bb = *(const bf16x8*)(wkv_b + (size_t)(256 + d) * 256 + kof);
      oa = __builtin_amdgcn_mfma_f32_16x16x32_bf16(a, bb, oa, 0, 0, 0);
    }
    float Av = kvA[256 + d], Bv = kvB[256 + d];
    #pragma unroll
    for (int r = 0; r < 4; r++) {
      int s = (quad << 2) + r;
      if (s < 8) updb[s * SP + d] = f2bf(oa[r] - cpl[s] * Av + Bv);
    }
  }
  __syncthreads();
  {
    f32x4 gi0 = 0.f, gi1 = 0.f, gi2 = 0.f, gh0 = 0.f, gh1 = 0.f, gh2 = 0.f;
    #pragma unroll
    for (int ks = 0; ks < 8; ks++) {
      int kof = (ks << 5) + kof0;
      bf16x8 au = *(const bf16x8*)&updb [arow + kof];
      bf16x8 ah = *(const bf16x8*)&slb_l[arow + kof];
      bf16x8 w0 = *(const bf16x8*)(wih_b + (size_t)(0 * 256 + d) * 256 + kof);
      bf16x8 w1r = *(const bf16x8*)(wih_b + (size_t)(1 * 256 + d) * 256 + kof);
      bf16x8 w2r = *(const bf16x8*)(wih_b + (size_t)(2 * 256 + d) * 256 + kof);
      bf16x8 u0 = *(const bf16x8*)(whh_b + (size_t)(0 * 256 + d) * 256 + kof);
      bf16x8 u1 = *(const bf16x8*)(whh_b + (size_t)(1 * 256 + d) * 256 + kof);
      bf16x8 u2 = *(const bf16x8*)(whh_b + (size_t)(2 * 256 + d) * 256 + kof);
      gi0 = __builtin_amdgcn_mfma_f32_16x16x32_bf16(au, w0, gi0, 0, 0, 0);
      gi1 = __builtin_amdgcn_mfma_f32_16x16x32_bf16(au, w1r, gi1, 0, 0, 0);
      gi2 = __builtin_amdgcn_mfma_f32_16x16x32_bf16(au, w2r, gi2, 0, 0, 0);
      gh0 = __builtin_amdgcn_mfma_f32_16x16x32_bf16(ah, u0, gh0, 0, 0, 0);
      gh1 = __builtin_amdgcn_mfma_f32_16x16x32_bf16(ah, u1, gh1, 0, 0, 0);
      gh2 = __builtin_amdgcn_mfma_f32_16x16x32_bf16(ah, u2, gh2, 0, 0, 0);
    }
    float bi0 = bih[d], bi1 = bih[256 + d], bi2 = bih[512 + d];
    float bh0 = bhh[d], bh1 = bhh[256 + d], bh2 = bhh[512 + d];
    #pragma unroll
    for (int r = 0; r < 4; r++) {
      int s = (quad << 2) + r;
      if (s < 8) {
        float rg = 1.f / (1.f + __expf(-(gi0[r] + bi0 + gh0[r] + bh0)));
        float zg = 1.f / (1.f + __expf(-(gi1[r] + bi1 + gh1[r] + bh1)));
        float ng = tanhf(gi2[r] + bi2 + rg * (gh2[r] + bh2));
        sl[s][d] = (1.f - zg) * ng + zg * sl[s][d];
      }
    }
  }
  __syncthreads();
  if (wave < 8) {
    float a0 = 0.f, a1 = 0.f;
    #pragma unroll
    for (int j = 0; j < 4; j++) { float v = sl[wave][lane + (j << 6)]; a0 += v; a1 += v * v; }
    #pragma unroll
    for (int m = 1; m < 64; m <<= 1) { a0 += __shfl_xor(a0, m); a1 += __shfl_xor(a1, m); }
    if (lane == 0) {
      float mn = a0 * (1.f / 256.f);
      float var = a1 * (1.f / 256.f) - mn * mn;
      mus[wave] = mn; rss[wave] = rsqrtf(var + EPSV);
    }
  }
  __syncthreads();
  for (int idx = t; idx < 2048; idx += 1024) {
    int s = idx >> 8, c = idx & 255;
    lnmb[s * SP + c] = f2bf((sl[s][c] - mus[s]) * rss[s] * lmg[c] + lmb[c]);
  }
  __syncthreads();
  {
    f32x4 ha = 0.f;
    #pragma unroll
    for (int ks = 0; ks < 8; ks++) {
      int kof = (ks << 5) + kof0;
      bf16x8 a = *(const bf16x8*)&lnmb[arow + kof];
      bf16x8 bb = *(const bf16x8*)(w1_b + (size_t)d * 256 + kof);
      ha = __builtin_amdgcn_mfma_f32_16x16x32_bf16(a, bb, ha, 0, 0, 0);
    }
    float bb1 = b1[d];
    #pragma unroll
    for (int r = 0; r < 4; r++) {
      int s = (quad << 2) + r;
      if (s < 8) hmb[s * SP + d] = f2bf(fmaxf(ha[r] + bb1, 0.f));
    }
  }
  __syncthreads();
  {
    f32x4 oa = 0.f;
    #pragma unroll
    for (int ks = 0; ks < 8; ks++) {
      int kof = (ks << 5) + kof0;
      bf16x8 a = *(const bf16x8*)&hmb[arow + kof];
      bf16x8 bb = *(const bf16x8*)(w2_b + (size_t)d * 256 + kof);
      oa = __builtin_amdgcn_mfma_f32_16x16x32_bf16(a, bb, oa, 0, 0, 0);
    }
    float bb2 = b2[d];
    #pragma unroll
    for (int r = 0; r < 4; r++) {
      int s = (quad << 2) + r;
      if (s < 8) sl[s][d] = sl[s][d] + oa[r] + bb2;
    }
  }
  __syncthreads();
  if (last) {
    for (int idx = t; idx < 2048; idx += 1024)
      out[(b << 11) + idx] = sl[idx >> 8][idx & 255];
    return;
  }
  for (int idx = t; idx < 2048; idx += 1024) {
    float v = sl[idx >> 8][idx & 255];
    slbuf[(b << 11) + idx] = v;
    slbG[(b << 11) + idx] = f2bf(v);
  }
  if (wave < 8) {
    float a0 = 0.f, a1 = 0.f;
    #pragma unroll
    for (int j = 0; j < 4; j++) { float v = sl[wave][lane + (j << 6)]; a0 += v; a1 += v * v; }
    #pragma unroll
    for (int m = 1; m < 64; m <<= 1) { a0 += __shfl_xor(a0, m); a1 += __shfl_xor(a1, m); }
    if (lane == 0) {
      float mn = a0 * (1.f / 256.f);
      float var = a1 * (1.f / 256.f) - mn * mn;
      mus[wave] = mn; rss[wave] = rsqrtf(var + EPSV);
    }
  }
  __syncthreads();
  for (int idx = t; idx < 2048; idx += 1024) {
    int s = idx >> 8, c = idx & 255;
    slnb[s * SP + c] = f2bf((sl[s][c] - mus[s]) * rss[s] * lsg[c] + lsb[c]);
  }
  __syncthreads();
  {
    f32x4 qa = 0.f;
    #pragma unroll
    for (int ks = 0; ks < 8; ks++) {
      int kof = (ks << 5) + kof0;
      bf16x8 a = *(const bf16x8*)&slnb[arow + kof];
      bf16x8 bb = *(const bf16x8*)(wq_b + (size_t)d * 256 + kof);
      qa = __builtin_amdgcn_mfma_f32_16x16x32_bf16(a, bb, qa, 0, 0, 0);
    }
    #pragma unroll
    for (int r = 0; r < 4; r++) {
      int s = (quad << 2) + r;
      if (s < 8) qlds[s * SP + d] = f2bf(qa[r]);
    }
  }
  __syncthreads();
  {
    f32x4 qa = 0.f;
    #pragma unroll
    for (int ks = 0; ks < 8; ks++) {
      int kof = (ks << 5) + kof0;
      bf16x8 a = *(const bf16x8*)&qlds[arow + kof];
      bf16x8 bb = *(const bf16x8*)(wkT_b + (size_t)d * 256 + kof);
      qa = __builtin_amdgcn_mfma_f32_16x16x32_bf16(a, bb, qa, 0, 0, 0);
    }
    #pragma unroll
    for (int r = 0; r < 4; r++) {
      int s = (quad << 2) + r;
      if (s < 8) qb[(b << 11) + (s << 8) + d] = f2bf(qa[r]);
    }
  }
  if (wave < 8) {
    int s = wave;
    float a0 = 0.f, a1 = 0.f;
    #pragma unroll
    for (int j = 0; j < 4; j++) {
      int dd = lane + (j << 6);
      float qv = b2f(qlds[s * SP + dd]);
      a0 += qv * kvA[dd]; a1 += qv * kvB[dd];
    }
    #pragma unroll
    for (int m = 1; m < 64; m <<= 1) { a0 += __shfl_xor(a0, m); a1 += __shfl_xor(a1, m); }
    if (lane == 0) { AqB[(b << 3) + s] = a0; BqB[(b << 3) + s] = a1; }
  }
}

extern "C" void kernel_launch(void* const* d_in, const int* in_sizes, int n_in,
                              void* d_out, int out_size, void* d_ws, size_t ws_size,
                              hipStream_t stream) {
  const float* x        = (const float*)d_in[0];
  const float* slots_mu = (const float*)d_in[1];
  const float* ln_in_g  = (const float*)d_in[2];
  const float* ln_in_b  = (const float*)d_in[3];
  const float* wk       = (const float*)d_in[4];
  const float* wv       = (const float*)d_in[5];
  const float* ln_s_g   = (const float*)d_in[6];
  const float* ln_s_b   = (const float*)d_in[7];
  const float* wq       = (const float*)d_in[8];
  const float* wih      = (const float*)d_in[9];
  const float* whh      = (const float*)d_in[10];
  const float* bih      = (const float*)d_in[11];
  const float* bhh      = (const float*)d_in[12];
  const float* lmg      = (const float*)d_in[13];
  const float* lmb      = (const float*)d_in[14];
  const float* w1       = (const float*)d_in[15];
  const float* b1       = (const float*)d_in[16];
  const float* w2       = (const float*)d_in[17];
  const float* b2       = (const float*)d_in[18];
  float* out = (float*)d_out;
  float* out_attn = out + 131072;

  char* ws = (char*)d_ws;
  short* xT     = (short*)(ws);                  // 33,554,432
  short* wkv_b  = (short*)(ws + 67108864);       //    262,144
  short* wq_b   = (short*)(ws + 67371008);       //    131,072
  short* wih_b  = (short*)(ws + 67502080);       //    393,216
  short* whh_b  = (short*)(ws + 67895296);       //    393,216
  short* w1_b   = (short*)(ws + 68288512);       //    131,072
  short* w2_b   = (short*)(ws + 68419584);       //    131,072
  float* slbuf  = (float*)(ws + 68550656);       //    524,288
  short* slbG   = (short*)(ws + 69074944);       //    262,144
  short* qb     = (short*)(ws + 69337088);       //    262,144
  short* parts  = (short*)(ws + 69599232);       //  4,194,304
  float* kvA    = (float*)(ws + 73793536);       //      2,048
  float* kvB    = (float*)(ws + 73795584);       //      2,048
  float* muB    = (float*)(ws + 73797632);       //    262,144
  float* rstdB  = (float*)(ws + 74059776);       //    262,144
  short* wkT_b  = (short*)(ws + 74321920);       //    131,072
  short* muO    = (short*)(ws + 74452992);       //    131,072
  float* cpbuf  = (float*)(ws + 74584064);       //     32,768
  float* AqB    = (float*)(ws + 74616832);       //      2,048
  float* BqB    = (float*)(ws + 74618880);       //      2,048 -> 74,620,928

  wcvt<<<2304, 256, 0, stream>>>(wq, wih, whh, w1, w2,
                                 wq_b, wih_b, whh_b, w1_b, w2_b);
  wfold<<<512, 256, 0, stream>>>(wk, wv, ln_in_g, ln_in_b, wkv_b, wkT_b, kvA, kvB);
  xt_stats<<<dim3(32, 64), 256, 0, stream>>>(x, xT, muB, rstdB, muO);
  slot_init<<<64, 256, 0, stream>>>(slots_mu, ln_s_g, ln_s_b, wq_b, wkT_b,
                                    kvA, kvB, slbuf, slbG, qb, AqB, BqB);
  for (int it = 0; it < 3; it++) {
    attn_heavy<<<dim3(16, 64), 256, 0, stream>>>(xT, x, qb, muB, rstdB, muO,
                                                 AqB, BqB, parts, cpbuf, out_attn,
                                                 (it == 2) ? 1 : 0);
    slot_reduce<<<64, 1024, 0, stream>>>(parts, cpbuf, slbuf, slbG, qb,
                                         wkv_b, wkT_b, kvA, kvB,
                                         wih_b, whh_b, bih, bhh, lmg, lmb,
                                         w1_b, b1, w2_b, b2, ln_s_g, ln_s_b, wq_b,
                                         AqB, BqB, out, (it == 2) ? 1 : 0);
  }
}

// Round 10
// 344.905 us; speedup vs baseline: 1.1445x; 1.0259x over previous
//
#include <hip/hip_runtime.h>

#define NPIX 1024
#define CIN  256
#define EPSV 1e-5f
#define SP 264
#define AP 72

typedef __attribute__((ext_vector_type(8))) short bf16x8;
typedef __attribute__((ext_vector_type(4))) float f32x4;

__device__ __forceinline__ short f2bf(float f) {
  unsigned u = __float_as_uint(f);
  unsigned r = (u + 0x7FFFu + ((u >> 16) & 1u)) >> 16;
  return (short)r;
}
__device__ __forceinline__ float b2f(short s) {
  return __uint_as_float(((unsigned)(unsigned short)s) << 16);
}

// ---------------- K0a: non-kv weights fp32 -> bf16 --------------------------
__global__ __launch_bounds__(256) void wcvt(
    const float* __restrict__ wq, const float* __restrict__ wih,
    const float* __restrict__ whh, const float* __restrict__ w1,
    const float* __restrict__ w2,
    short* __restrict__ wq_b, short* __restrict__ wih_b, short* __restrict__ whh_b,
    short* __restrict__ w1_b, short* __restrict__ w2_b) {
  int id = blockIdx.x * 256 + threadIdx.x;
  if      (id <  65536) wq_b [id         ] = f2bf(wq [id         ]);
  else if (id < 262144) wih_b[id -  65536] = f2bf(wih[id -  65536]);
  else if (id < 458752) whh_b[id - 262144] = f2bf(whh[id - 262144]);
  else if (id < 524288) w1_b [id - 458752] = f2bf(w1 [id - 458752]);
  else if (id < 589824) w2_b [id - 524288] = f2bf(w2 [id - 524288]);
}

// ---------------- K0b: wkv'=g*w (bf16) + wkT (transposed Wk') + A,B sums ----
__global__ __launch_bounds__(256) void wfold(
    const float* __restrict__ wk, const float* __restrict__ wv,
    const float* __restrict__ g, const float* __restrict__ bet,
    short* __restrict__ wkv_b, short* __restrict__ wkT_b,
    float* __restrict__ kvA, float* __restrict__ kvB) {
  __shared__ float ra[4], rb[4];
  int d = blockIdx.x;                 // 0..511
  int t = threadIdx.x;
  const float* wrow = (d < 256) ? (wk + (size_t)d * 256) : (wv + (size_t)(d - 256) * 256);
  float w = wrow[t], gg = g[t], bb = bet[t];
  float pa = gg * w, pb = bb * w;
  short hv = f2bf(pa);
  wkv_b[(size_t)d * 256 + t] = hv;
  if (d < 256) wkT_b[(size_t)t * 256 + d] = hv;   // Wk'^T[c][d]
  #pragma unroll
  for (int m = 1; m < 64; m <<= 1) { pa += __shfl_xor(pa, m); pb += __shfl_xor(pb, m); }
  int wave = t >> 6, lane = t & 63;
  if (lane == 0) { ra[wave] = pa; rb[wave] = pb; }
  __syncthreads();
  if (t == 0) {
    kvA[d] = ra[0] + ra[1] + ra[2] + ra[3];
    kvB[d] = rb[0] + rb[1] + rb[2] + rb[3];
  }
}

// ---------------- K1: x -> xT bf16 (transposed) + LN stats ------------------
__global__ __launch_bounds__(256) void xt_stats(
    const float* __restrict__ x, short* __restrict__ xT,
    float* __restrict__ mu, float* __restrict__ rstd, short* __restrict__ muO) {
  __shared__ float ps[32][9], pq[32][9];
  int t = threadIdx.x;
  int pt = blockIdx.x, b = blockIdx.y;
  int j = t & 3, pql = (t >> 2) & 7, cg = t >> 5;
  int P0 = (pt << 5) + (pql << 2);
  const float* xb = x + (size_t)b * CIN * NPIX;
  short* xrow = xT + (size_t)((b << 10) + P0 + j) * 256 + (cg << 5);
  float s = 0.f, sq = 0.f;
  bf16x8 o;
  #pragma unroll
  for (int i = 0; i < 8; i++) {
    int c0 = (cg << 5) + (i << 2);
    float4 v = *(const float4*)(xb + (size_t)(c0 + j) * NPIX + P0);
    float v0 = v.x, v1 = v.y, v2 = v.z, v3 = v.w;
    float e0 = __shfl_xor((j & 1) ? v0 : v1, 1);
    float e1 = __shfl_xor((j & 1) ? v2 : v3, 1);
    if (j & 1) { v0 = e0; v2 = e1; } else { v1 = e0; v3 = e1; }
    float e2 = __shfl_xor((j & 2) ? v0 : v2, 2);
    float e3 = __shfl_xor((j & 2) ? v1 : v3, 2);
    if (j & 2) { v0 = e2; v1 = e3; } else { v2 = e2; v3 = e3; }
    s += v0 + v1 + v2 + v3;
    sq += v0 * v0 + v1 * v1 + v2 * v2 + v3 * v3;
    int h = (i & 1) << 2;
    o[h + 0] = f2bf(v0); o[h + 1] = f2bf(v1); o[h + 2] = f2bf(v2); o[h + 3] = f2bf(v3);
    if (i & 1) *(bf16x8*)(xrow + ((i - 1) << 2)) = o;
  }
  ps[(pql << 2) + j][cg] = s;
  pq[(pql << 2) + j][cg] = sq;
  __syncthreads();
  if (t < 32) {
    float ss = 0.f, qq = 0.f;
    #pragma unroll
    for (int g2 = 0; g2 < 8; g2++) { ss += ps[t][g2]; qq += pq[t][g2]; }
    float m = ss * (1.f / 256.f);
    float var = qq * (1.f / 256.f) - m * m;
    int p = (b << 10) + (pt << 5) + t;
    mu[p] = m;
    rstd[p] = rsqrtf(var + EPSV);
    muO[p] = f2bf(m);
  }
}

// ---------------- K3: slot init — slots, LN_s, q0 -> qk0, Aq0/Bq0 -----------
__global__ __launch_bounds__(256) void slot_init(
    const float* __restrict__ slots_mu,
    const float* __restrict__ lsg, const float* __restrict__ lsb,
    const short* __restrict__ wq_b, const short* __restrict__ wkT_b,
    const float* __restrict__ kvA, const float* __restrict__ kvB,
    float* __restrict__ slbuf, short* __restrict__ slbG, short* __restrict__ qb,
    float* __restrict__ AqB, float* __restrict__ BqB) {
  __shared__ float sl[8][256];
  __shared__ float mus[8], rss[8];
  __shared__ __align__(16) short slnb[8 * SP], qlds[8 * SP];
  int b = blockIdx.x, t = threadIdx.x;
  int wave = t >> 6, lane = t & 63, quad = lane >> 4, lid = lane & 15;
  int arow = (lid & 7) * SP, kof0 = quad << 3;
  for (int idx = t; idx < 2048; idx += 256) {
    float v = slots_mu[idx];
    sl[idx >> 8][idx & 255] = v;
    slbuf[(b << 11) + idx] = v;
    slbG[(b << 11) + idx] = f2bf(v);
  }
  __syncthreads();
  {
    int s0 = (wave << 1) + (lane >> 5);
    int l32 = lane & 31;
    float a0 = 0.f, a1 = 0.f;
    #pragma unroll
    for (int j = 0; j < 8; j++) { float v = sl[s0][l32 + (j << 5)]; a0 += v; a1 += v * v; }
    #pragma unroll
    for (int m = 1; m < 32; m <<= 1) { a0 += __shfl_xor(a0, m); a1 += __shfl_xor(a1, m); }
    if (l32 == 0) {
      float mn = a0 * (1.f / 256.f);
      float var = a1 * (1.f / 256.f) - mn * mn;
      mus[s0] = mn; rss[s0] = rsqrtf(var + EPSV);
    }
  }
  __syncthreads();
  for (int idx = t; idx < 2048; idx += 256) {
    int s = idx >> 8, c = idx & 255;
    slnb[s * SP + c] = f2bf((sl[s][c] - mus[s]) * rss[s] * lsg[c] + lsb[c]);
  }
  __syncthreads();
  #pragma unroll
  for (int nt = 0; nt < 4; nt++) {
    int d = (wave << 6) + (nt << 4) + lid;
    bf16x8 wf[8];
    #pragma unroll
    for (int ks = 0; ks < 8; ks++)
      wf[ks] = *(const bf16x8*)(wq_b + (size_t)d * 256 + (ks << 5) + kof0);
    f32x4 qa = 0.f;
    #pragma unroll
    for (int ks = 0; ks < 8; ks++) {
      bf16x8 a = *(const bf16x8*)&slnb[arow + (ks << 5) + kof0];
      qa = __builtin_amdgcn_mfma_f32_16x16x32_bf16(a, wf[ks], qa, 0, 0, 0);
    }
    #pragma unroll
    for (int r = 0; r < 4; r++) {
      int s = (quad << 2) + r;
      if (s < 8) qlds[s * SP + d] = f2bf(qa[r]);
    }
  }
  __syncthreads();
  #pragma unroll
  for (int nt = 0; nt < 4; nt++) {
    int c = (wave << 6) + (nt << 4) + lid;
    bf16x8 wf[8];
    #pragma unroll
    for (int ks = 0; ks < 8; ks++)
      wf[ks] = *(const bf16x8*)(wkT_b + (size_t)c * 256 + (ks << 5) + kof0);
    f32x4 qa = 0.f;
    #pragma unroll
    for (int ks = 0; ks < 8; ks++) {
      bf16x8 a = *(const bf16x8*)&qlds[arow + (ks << 5) + kof0];
      qa = __builtin_amdgcn_mfma_f32_16x16x32_bf16(a, wf[ks], qa, 0, 0, 0);
    }
    #pragma unroll
    for (int r = 0; r < 4; r++) {
      int s = (quad << 2) + r;
      if (s < 8) qb[(b << 11) + (s << 8) + c] = f2bf(qa[r]);
    }
  }
  for (int s = wave; s < 8; s += 4) {
    float a0 = 0.f, a1 = 0.f;
    #pragma unroll
    for (int j = 0; j < 4; j++) {
      int dd = lane + (j << 6);
      float qv = b2f(qlds[s * SP + dd]);
      a0 += qv * kvA[dd]; a1 += qv * kvB[dd];
    }
    #pragma unroll
    for (int m = 1; m < 64; m <<= 1) { a0 += __shfl_xor(a0, m); a1 += __shfl_xor(a1, m); }
    if (lane == 0) { AqB[(b << 3) + s] = a0; BqB[(b << 3) + s] = a1; }
  }
}

// ---------------- K4: heavy — logits(+LN corr) + softmax + y,cp -------------
// grid (16 chunks, 64 b), block 256. All global loads batch-hoisted.
__global__ __launch_bounds__(256, 4) void attn_heavy(
    const short* __restrict__ xT, const float* __restrict__ x,
    const short* __restrict__ qb,
    const float* __restrict__ muB, const float* __restrict__ rstdB,
    const short* __restrict__ muO,
    const float* __restrict__ AqB, const float* __restrict__ BqB,
    short* __restrict__ partials, float* __restrict__ cpbuf,
    float* __restrict__ out_attn, int write_attn) {
  __shared__ __align__(16) short attT[8 * AP];
  int chunk = blockIdx.x, b = blockIdx.y;
  int t = threadIdx.x, wave = t >> 6, lane = t & 63, quad = lane >> 4, lid = lane & 15;
  int kof0 = quad << 3;
  bf16x8 qf[8];
  const short* qpb = qb + ((size_t)b << 11) + (lid & 7) * 256 + kof0;
  #pragma unroll
  for (int ks = 0; ks < 8; ks++) qf[ks] = *(const bf16x8*)(qpb + (ks << 5));
  float Aq = AqB[(b << 3) + (lid & 7)];
  float Bq = BqB[(b << 3) + (lid & 7)];
  {
    int p0l = wave << 4;
    int pbase = (b << 10) + (chunk << 6) + p0l;
    const short* kb = xT + ((size_t)(pbase + lid)) * 256 + kof0;
    bf16x8 kfr[8];
    #pragma unroll
    for (int ks = 0; ks < 8; ks++) kfr[ks] = *(const bf16x8*)(kb + (ks << 5));
    f32x4 la = 0.f;
    #pragma unroll
    for (int ks = 0; ks < 8; ks++)
      la = __builtin_amdgcn_mfma_f32_16x16x32_bf16(kfr[ks], qf[ks], la, 0, 0, 0);
    #pragma unroll
    for (int r = 0; r < 4; r++) {
      int p = pbase + (quad << 2) + r;
      float rs = rstdB[p], mm = muB[p];
      float lg = (rs * (la[r] - mm * Aq) + Bq) * 0.0625f;
      float mx = lg;
      #pragma unroll
      for (int m = 1; m < 16; m <<= 1) mx = fmaxf(mx, __shfl_xor(mx, m));
      float e = __expf(lg - mx);
      float sm = e;
      #pragma unroll
      for (int m = 1; m < 16; m <<= 1) sm += __shfl_xor(sm, m);
      float at = (e + e) / sm;
      if (lid < 8) {
        int pl = p0l + (quad << 2) + r;
        attT[lid * AP + pl] = f2bf(at * rs);   // fold rstd into attn weight
        if (write_attn) {
          int pg = (chunk << 6) + pl;
          out_attn[((size_t)b << 13) + (pg << 3) + lid] = at;
        }
      }
    }
  }
  __syncthreads();
  // y partials = attn'^T @ bf16(x); x float4 loads hoisted across nt
  #pragma unroll
  for (int nt = 0; nt < 4; nt++) {
    int d0 = (wave << 6) + (nt << 4);
    const float* xf = x + (size_t)b * 262144 + (size_t)(d0 + lid) * 1024
                      + (chunk << 6) + kof0;
    float4 va0 = *(const float4*)xf;
    float4 vb0 = *(const float4*)(xf + 4);
    float4 va1 = *(const float4*)(xf + 32);
    float4 vb1 = *(const float4*)(xf + 36);
    bf16x8 bb0, bb1;
    bb0[0] = f2bf(va0.x); bb0[1] = f2bf(va0.y); bb0[2] = f2bf(va0.z); bb0[3] = f2bf(va0.w);
    bb0[4] = f2bf(vb0.x); bb0[5] = f2bf(vb0.y); bb0[6] = f2bf(vb0.z); bb0[7] = f2bf(vb0.w);
    bb1[0] = f2bf(va1.x); bb1[1] = f2bf(va1.y); bb1[2] = f2bf(va1.z); bb1[3] = f2bf(va1.w);
    bb1[4] = f2bf(vb1.x); bb1[5] = f2bf(vb1.y); bb1[6] = f2bf(vb1.z); bb1[7] = f2bf(vb1.w);
    f32x4 ua = 0.f;
    bf16x8 a0 = *(const bf16x8*)&attT[(lid & 7) * AP + kof0];
    bf16x8 a1 = *(const bf16x8*)&attT[(lid & 7) * AP + 32 + kof0];
    ua = __builtin_amdgcn_mfma_f32_16x16x32_bf16(a0, bb0, ua, 0, 0, 0);
    ua = __builtin_amdgcn_mfma_f32_16x16x32_bf16(a1, bb1, ua, 0, 0, 0);
    #pragma unroll
    for (int r = 0; r < 4; r++) {
      int s = (quad << 2) + r;
      if (s < 8)
        partials[(((size_t)(b << 4) + chunk) << 11) + (s << 8) + d0 + lid] = f2bf(ua[r]);
    }
  }
  // cp partials = attn'^T @ mu
  if (wave == 0) {
    f32x4 ca = 0.f;
    #pragma unroll
    for (int ks = 0; ks < 2; ks++) {
      bf16x8 a = *(const bf16x8*)&attT[(lid & 7) * AP + (ks << 5) + kof0];
      bf16x8 bm = *(const bf16x8*)(muO + (b << 10) + (chunk << 6) + (ks << 5) + kof0);
      ca = __builtin_amdgcn_mfma_f32_16x16x32_bf16(a, bm, ca, 0, 0, 0);
    }
    if (lid == 0) {
      #pragma unroll
      for (int r = 0; r < 4; r++) {
        int s = (quad << 2) + r;
        if (s < 8) cpbuf[(((b << 4) + chunk) << 3) + s] = ca[r];
      }
    }
  }
}

// ---------------- K5: reduce y,cp + updates + GRU + MLP + (qk next) ---------
// block 1024, min 4 waves/EU declared -> 128 VGPR budget; all weight loads
// hoisted into register batches so they issue in parallel (R9: 48 VGPRs
// serialized ~88 LLC round-trips/wave -> 48us stall).
__global__ __launch_bounds__(1024, 4) void slot_reduce(
    const short* __restrict__ partials, const float* __restrict__ cpbuf,
    float* __restrict__ slbuf, short* __restrict__ slbG, short* __restrict__ qb,
    const short* __restrict__ wkv_b, const short* __restrict__ wkT_b,
    const float* __restrict__ kvA, const float* __restrict__ kvB,
    const short* __restrict__ wih_b, const short* __restrict__ whh_b,
    const float* __restrict__ bih, const float* __restrict__ bhh,
    const float* __restrict__ lmg, const float* __restrict__ lmb,
    const short* __restrict__ w1_b, const float* __restrict__ b1,
    const short* __restrict__ w2_b, const float* __restrict__ b2,
    const float* __restrict__ lsg, const float* __restrict__ lsb,
    const short* __restrict__ wq_b,
    float* __restrict__ AqB, float* __restrict__ BqB,
    float* __restrict__ out, int last) {
  __shared__ float sl[8][256];
  __shared__ float mus[8], rss[8], cpl[8];
  __shared__ __align__(16) short ylds[8 * SP], updb[8 * SP], slb_l[8 * SP],
                                  lnmb[8 * SP], hmb[8 * SP], slnb[8 * SP], qlds[8 * SP];
  int b = blockIdx.x, t = threadIdx.x;
  int wave = t >> 6, lane = t & 63, quad = lane >> 4, lid = lane & 15;
  int arow = (lid & 7) * SP, kof0 = quad << 3;
  int d = (wave << 4) + lid;
  // ---- stage 0: parallel partial reduce + slot staging + cp reduce
  if (t < 256) {
    int s = t >> 5, d8 = (t & 31) << 3;
    bf16x8 vv[16];
    #pragma unroll
    for (int c = 0; c < 16; c++)
      vv[c] = *(const bf16x8*)(partials + ((((size_t)(b << 4) + c) << 11) + (s << 8) + d8));
    float acc[8];
    #pragma unroll
    for (int i = 0; i < 8; i++) acc[i] = 0.f;
    #pragma unroll
    for (int c = 0; c < 16; c++)
      #pragma unroll
      for (int i = 0; i < 8; i++) acc[i] += b2f(vv[c][i]);
    bf16x8 o;
    #pragma unroll
    for (int i = 0; i < 8; i++) o[i] = f2bf(acc[i]);
    *(bf16x8*)&ylds[s * SP + d8] = o;
  } else if (t < 512) {
    int tt = t - 256;
    int s = tt >> 5, d8 = (tt & 31) << 3;
    bf16x8 v = *(const bf16x8*)(slbG + ((b << 11) + (s << 8) + d8));
    *(bf16x8*)&slb_l[s * SP + d8] = v;
  } else if (t < 768) {
    int tt = t - 512;
    int s = tt >> 5, d8 = (tt & 31) << 3;
    float4 v0 = *(const float4*)(slbuf + ((b << 11) + (s << 8) + d8));
    float4 v1 = *(const float4*)(slbuf + ((b << 11) + (s << 8) + d8 + 4));
    *(float4*)&sl[s][d8] = v0;
    *(float4*)&sl[s][d8 + 4] = v1;
  } else if (t < 776) {
    int s = t - 768;
    float c = 0.f;
    #pragma unroll
    for (int cc = 0; cc < 16; cc++) c += cpbuf[(((b << 4) + cc) << 3) + s];
    cpl[s] = c;
  }
  // prefetch v-weights + biases while stage-0 staging settles
  bf16x8 wvf[8];
  #pragma unroll
  for (int ks = 0; ks < 8; ks++)
    wvf[ks] = *(const bf16x8*)(wkv_b + (size_t)(256 + d) * 256 + (ks << 5) + kof0);
  float Av = kvA[256 + d], Bv = kvB[256 + d];
  float bi0 = bih[d], bi1 = bih[256 + d], bi2 = bih[512 + d];
  float bh0 = bhh[d], bh1 = bhh[256 + d], bh2 = bhh[512 + d];
  __syncthreads();
  // ---- stage 0.5: updates = y @ Wv'^T - cp*Av + Bv
  {
    f32x4 oa = 0.f;
    #pragma unroll
    for (int ks = 0; ks < 8; ks++) {
      bf16x8 a = *(const bf16x8*)&ylds[arow + (ks << 5) + kof0];
      oa = __builtin_amdgcn_mfma_f32_16x16x32_bf16(a, wvf[ks], oa, 0, 0, 0);
    }
    #pragma unroll
    for (int r = 0; r < 4; r++) {
      int s = (quad << 2) + r;
      if (s < 8) updb[s * SP + d] = f2bf(oa[r] - cpl[s] * Av + Bv);
    }
  }
  __syncthreads();
  // ---- stage 1: GRU — 6 gate GEMMs, weights hoisted in 2-ks batches
  {
    f32x4 gi0 = 0.f, gi1 = 0.f, gi2 = 0.f, gh0 = 0.f, gh1 = 0.f, gh2 = 0.f;
    size_t r0 = (size_t)d * 256, r1 = (size_t)(256 + d) * 256, r2 = (size_t)(512 + d) * 256;
    #pragma unroll
    for (int kb = 0; kb < 4; kb++) {
      int k0 = (kb << 6) + kof0, k1 = k0 + 32;
      bf16x8 f0 = *(const bf16x8*)(wih_b + r0 + k0);
      bf16x8 f1 = *(const bf16x8*)(wih_b + r1 + k0);
      bf16x8 f2 = *(const bf16x8*)(wih_b + r2 + k0);
      bf16x8 f3 = *(const bf16x8*)(whh_b + r0 + k0);
      bf16x8 f4 = *(const bf16x8*)(whh_b + r1 + k0);
      bf16x8 f5 = *(const bf16x8*)(whh_b + r2 + k0);
      bf16x8 f6 = *(const bf16x8*)(wih_b + r0 + k1);
      bf16x8 f7 = *(const bf16x8*)(wih_b + r1 + k1);
      bf16x8 f8 = *(const bf16x8*)(wih_b + r2 + k1);
      bf16x8 f9 = *(const bf16x8*)(whh_b + r0 + k1);
      bf16x8 fa = *(const bf16x8*)(whh_b + r1 + k1);
      bf16x8 fb = *(const bf16x8*)(whh_b + r2 + k1);
      bf16x8 a0u = *(const bf16x8*)&updb [arow + k0];
      bf16x8 a0h = *(const bf16x8*)&slb_l[arow + k0];
      bf16x8 a1u = *(const bf16x8*)&updb [arow + k1];
      bf16x8 a1h = *(const bf16x8*)&slb_l[arow + k1];
      gi0 = __builtin_amdgcn_mfma_f32_16x16x32_bf16(a0u, f0, gi0, 0, 0, 0);
      gi1 = __builtin_amdgcn_mfma_f32_16x16x32_bf16(a0u, f1, gi1, 0, 0, 0);
      gi2 = __builtin_amdgcn_mfma_f32_16x16x32_bf16(a0u, f2, gi2, 0, 0, 0);
      gh0 = __builtin_amdgcn_mfma_f32_16x16x32_bf16(a0h, f3, gh0, 0, 0, 0);
      gh1 = __builtin_amdgcn_mfma_f32_16x16x32_bf16(a0h, f4, gh1, 0, 0, 0);
      gh2 = __builtin_amdgcn_mfma_f32_16x16x32_bf16(a0h, f5, gh2, 0, 0, 0);
      gi0 = __builtin_amdgcn_mfma_f32_16x16x32_bf16(a1u, f6, gi0, 0, 0, 0);
      gi1 = __builtin_amdgcn_mfma_f32_16x16x32_bf16(a1u, f7, gi1, 0, 0, 0);
      gi2 = __builtin_amdgcn_mfma_f32_16x16x32_bf16(a1u, f8, gi2, 0, 0, 0);
      gh0 = __builtin_amdgcn_mfma_f32_16x16x32_bf16(a1h, f9, gh0, 0, 0, 0);
      gh1 = __builtin_amdgcn_mfma_f32_16x16x32_bf16(a1h, fa, gh1, 0, 0, 0);
      gh2 = __builtin_amdgcn_mfma_f32_16x16x32_bf16(a1h, fb, gh2, 0, 0, 0);
    }
    #pragma unroll
    for (int r = 0; r < 4; r++) {
      int s = (quad << 2) + r;
      if (s < 8) {
        float rg = 1.f / (1.f + __expf(-(gi0[r] + bi0 + gh0[r] + bh0)));
        float zg = 1.f / (1.f + __expf(-(gi1[r] + bi1 + gh1[r] + bh1)));
        float ng = tanhf(gi2[r] + bi2 + rg * (gh2[r] + bh2));
        sl[s][d] = (1.f - zg) * ng + zg * sl[s][d];
      }
    }
  }
  // prefetch MLP1 weights before LN barrier
  bf16x8 w1f[8];
  #pragma unroll
  for (int ks = 0; ks < 8; ks++)
    w1f[ks] = *(const bf16x8*)(w1_b + (size_t)d * 256 + (ks << 5) + kof0);
  float bb1 = b1[d];
  __syncthreads();
  // ---- stage 2: LN_m
  if (wave < 8) {
    float a0 = 0.f, a1 = 0.f;
    #pragma unroll
    for (int j = 0; j < 4; j++) { float v = sl[wave][lane + (j << 6)]; a0 += v; a1 += v * v; }
    #pragma unroll
    for (int m = 1; m < 64; m <<= 1) { a0 += __shfl_xor(a0, m); a1 += __shfl_xor(a1, m); }
    if (lane == 0) {
      float mn = a0 * (1.f / 256.f);
      float var = a1 * (1.f / 256.f) - mn * mn;
      mus[wave] = mn; rss[wave] = rsqrtf(var + EPSV);
    }
  }
  __syncthreads();
  for (int idx = t; idx < 2048; idx += 1024) {
    int s = idx >> 8, c = idx & 255;
    lnmb[s * SP + c] = f2bf((sl[s][c] - mus[s]) * rss[s] * lmg[c] + lmb[c]);
  }
  // prefetch MLP2 weights
  bf16x8 w2f[8];
  #pragma unroll
  for (int ks = 0; ks < 8; ks++)
    w2f[ks] = *(const bf16x8*)(w2_b + (size_t)d * 256 + (ks << 5) + kof0);
  float bb2 = b2[d];
  __syncthreads();
  // ---- stage 3: MLP layer 1
  {
    f32x4 ha = 0.f;
    #pragma unroll
    for (int ks = 0; ks < 8; ks++) {
      bf16x8 a = *(const bf16x8*)&lnmb[arow + (ks << 5) + kof0];
      ha = __builtin_amdgcn_mfma_f32_16x16x32_bf16(a, w1f[ks], ha, 0, 0, 0);
    }
    #pragma unroll
    for (int r = 0; r < 4; r++) {
      int s = (quad << 2) + r;
      if (s < 8) hmb[s * SP + d] = f2bf(fmaxf(ha[r] + bb1, 0.f));
    }
  }
  __syncthreads();
  // ---- stage 4: MLP layer 2 + residual
  {
    f32x4 oa = 0.f;
    #pragma unroll
    for (int ks = 0; ks < 8; ks++) {
      bf16x8 a = *(const bf16x8*)&hmb[arow + (ks << 5) + kof0];
      oa = __builtin_amdgcn_mfma_f32_16x16x32_bf16(a, w2f[ks], oa, 0, 0, 0);
    }
    #pragma unroll
    for (int r = 0; r < 4; r++) {
      int s = (quad << 2) + r;
      if (s < 8) sl[s][d] = sl[s][d] + oa[r] + bb2;
    }
  }
  __syncthreads();
  if (last) {
    for (int idx = t; idx < 2048; idx += 1024)
      out[(b << 11) + idx] = sl[idx >> 8][idx & 255];
    return;
  }
  // prefetch wq weights
  bf16x8 wqf[8];
  #pragma unroll
  for (int ks = 0; ks < 8; ks++)
    wqf[ks] = *(const bf16x8*)(wq_b + (size_t)d * 256 + (ks << 5) + kof0);
  // ---- stage 5: persist slots; LN_s; q -> qlds
  for (int idx = t; idx < 2048; idx += 1024) {
    float v = sl[idx >> 8][idx & 255];
    slbuf[(b << 11) + idx] = v;
    slbG[(b << 11) + idx] = f2bf(v);
  }
  if (wave < 8) {
    float a0 = 0.f, a1 = 0.f;
    #pragma unroll
    for (int j = 0; j < 4; j++) { float v = sl[wave][lane + (j << 6)]; a0 += v; a1 += v * v; }
    #pragma unroll
    for (int m = 1; m < 64; m <<= 1) { a0 += __shfl_xor(a0, m); a1 += __shfl_xor(a1, m); }
    if (lane == 0) {
      float mn = a0 * (1.f / 256.f);
      float var = a1 * (1.f / 256.f) - mn * mn;
      mus[wave] = mn; rss[wave] = rsqrtf(var + EPSV);
    }
  }
  __syncthreads();
  for (int idx = t; idx < 2048; idx += 1024) {
    int s = idx >> 8, c = idx & 255;
    slnb[s * SP + c] = f2bf((sl[s][c] - mus[s]) * rss[s] * lsg[c] + lsb[c]);
  }
  // prefetch wkT weights
  bf16x8 wkf[8];
  #pragma unroll
  for (int ks = 0; ks < 8; ks++)
    wkf[ks] = *(const bf16x8*)(wkT_b + (size_t)d * 256 + (ks << 5) + kof0);
  __syncthreads();
  {
    f32x4 qa = 0.f;
    #pragma unroll
    for (int ks = 0; ks < 8; ks++) {
      bf16x8 a = *(const bf16x8*)&slnb[arow + (ks << 5) + kof0];
      qa = __builtin_amdgcn_mfma_f32_16x16x32_bf16(a, wqf[ks], qa, 0, 0, 0);
    }
    #pragma unroll
    for (int r = 0; r < 4; r++) {
      int s = (quad << 2) + r;
      if (s < 8) qlds[s * SP + d] = f2bf(qa[r]);
    }
  }
  __syncthreads();
  // ---- stage 6: qk = q @ wkT rows; Aq/Bq dots
  {
    f32x4 qa = 0.f;
    #pragma unroll
    for (int ks = 0; ks < 8; ks++) {
      bf16x8 a = *(const bf16x8*)&qlds[arow + (ks << 5) + kof0];
      qa = __builtin_amdgcn_mfma_f32_16x16x32_bf16(a, wkf[ks], qa, 0, 0, 0);
    }
    #pragma unroll
    for (int r = 0; r < 4; r++) {
      int s = (quad << 2) + r;
      if (s < 8) qb[(b << 11) + (s << 8) + d] = f2bf(qa[r]);
    }
  }
  if (wave < 8) {
    int s = wave;
    float a0 = 0.f, a1 = 0.f;
    #pragma unroll
    for (int j = 0; j < 4; j++) {
      int dd = lane + (j << 6);
      float qv = b2f(qlds[s * SP + dd]);
      a0 += qv * kvA[dd]; a1 += qv * kvB[dd];
    }
    #pragma unroll
    for (int m = 1; m < 64; m <<= 1) { a0 += __shfl_xor(a0, m); a1 += __shfl_xor(a1, m); }
    if (lane == 0) { AqB[(b << 3) + s] = a0; BqB[(b << 3) + s] = a1; }
  }
}

extern "C" void kernel_launch(void* const* d_in, const int* in_sizes, int n_in,
                              void* d_out, int out_size, void* d_ws, size_t ws_size,
                              hipStream_t stream) {
  const float* x        = (const float*)d_in[0];
  const float* slots_mu = (const float*)d_in[1];
  const float* ln_in_g  = (const float*)d_in[2];
  const float* ln_in_b  = (const float*)d_in[3];
  const float* wk       = (const float*)d_in[4];
  const float* wv       = (const float*)d_in[5];
  const float* ln_s_g   = (const float*)d_in[6];
  const float* ln_s_b   = (const float*)d_in[7];
  const float* wq       = (const float*)d_in[8];
  const float* wih      = (const float*)d_in[9];
  const float* whh      = (const float*)d_in[10];
  const float* bih      = (const float*)d_in[11];
  const float* bhh      = (const float*)d_in[12];
  const float* lmg      = (const float*)d_in[13];
  const float* lmb      = (const float*)d_in[14];
  const float* w1       = (const float*)d_in[15];
  const float* b1       = (const float*)d_in[16];
  const float* w2       = (const float*)d_in[17];
  const float* b2       = (const float*)d_in[18];
  float* out = (float*)d_out;
  float* out_attn = out + 131072;

  char* ws = (char*)d_ws;
  short* xT     = (short*)(ws);                  // 33,554,432
  short* wkv_b  = (short*)(ws + 67108864);       //    262,144
  short* wq_b   = (short*)(ws + 67371008);       //    131,072
  short* wih_b  = (short*)(ws + 67502080);       //    393,216
  short* whh_b  = (short*)(ws + 67895296);       //    393,216
  short* w1_b   = (short*)(ws + 68288512);       //    131,072
  short* w2_b   = (short*)(ws + 68419584);       //    131,072
  float* slbuf  = (float*)(ws + 68550656);       //    524,288
  short* slbG   = (short*)(ws + 69074944);       //    262,144
  short* qb     = (short*)(ws + 69337088);       //    262,144
  short* parts  = (short*)(ws + 69599232);       //  4,194,304
  float* kvA    = (float*)(ws + 73793536);       //      2,048
  float* kvB    = (float*)(ws + 73795584);       //      2,048
  float* muB    = (float*)(ws + 73797632);       //    262,144
  float* rstdB  = (float*)(ws + 74059776);       //    262,144
  short* wkT_b  = (short*)(ws + 74321920);       //    131,072
  short* muO    = (short*)(ws + 74452992);       //    131,072
  float* cpbuf  = (float*)(ws + 74584064);       //     32,768
  float* AqB    = (float*)(ws + 74616832);       //      2,048
  float* BqB    = (float*)(ws + 74618880);       //      2,048 -> 74,620,928

  wcvt<<<2304, 256, 0, stream>>>(wq, wih, whh, w1, w2,
                                 wq_b, wih_b, whh_b, w1_b, w2_b);
  wfold<<<512, 256, 0, stream>>>(wk, wv, ln_in_g, ln_in_b, wkv_b, wkT_b, kvA, kvB);
  xt_stats<<<dim3(32, 64), 256, 0, stream>>>(x, xT, muB, rstdB, muO);
  slot_init<<<64, 256, 0, stream>>>(slots_mu, ln_s_g, ln_s_b, wq_b, wkT_b,
                                    kvA, kvB, slbuf, slbG, qb, AqB, BqB);
  for (int it = 0; it < 3; it++) {
    attn_heavy<<<dim3(16, 64), 256, 0, stream>>>(xT, x, qb, muB, rstdB, muO,
                                                 AqB, BqB, parts, cpbuf, out_attn,
                                                 (it == 2) ? 1 : 0);
    slot_reduce<<<64, 1024, 0, stream>>>(parts, cpbuf, slbuf, slbG, qb,
                                         wkv_b, wkT_b, kvA, kvB,
                                         wih_b, whh_b, bih, bhh, lmg, lmb,
                                         w1_b, b1, w2_b, b2, ln_s_g, ln_s_b, wq_b,
                                         AqB, BqB, out, (it == 2) ? 1 : 0);
  }
}